// Round 1
// baseline (516.892 us; speedup 1.0000x reference)
//
#include <hip/hip_runtime.h>
#include <math.h>

#define B_   16
#define N_   2000
#define F_   128
#define D_   64
#define H_   4
#define OW_  200
#define K_   20
#define BN_  (B_*N_)      // 32000
#define HD_  (H_*D_)      // 256
#define EPS_ 1e-5f

// ---------------------------------------------------------------- norms
__global__ __launch_bounds__(256) void k_norms(const float* __restrict__ emb,
                                               float* __restrict__ nrm) {
    int i = blockIdx.x * blockDim.x + threadIdx.x;
    if (i < N_) {
        const float* e = emb + (size_t)i * D_;
        float s = 0.f;
        #pragma unroll
        for (int d = 0; d < D_; ++d) s += e[d] * e[d];
        nrm[i] = sqrtf(s);
    }
}

// ---------------------------------------------------------------- top-k (block per row)
__global__ __launch_bounds__(256) void k_topk(const float* __restrict__ emb,
                                              const float* __restrict__ nrm,
                                              int* __restrict__ topk) {
    const int i = blockIdx.x;
    const int t = threadIdx.x;
    __shared__ float cosL[2048];
    __shared__ float er[D_];
    __shared__ float redV[4];
    __shared__ int   redI[4];

    if (t < D_) er[t] = emb[(size_t)i * D_ + t];
    __syncthreads();

    const float rni = nrm[i];
    for (int j = t; j < 2048; j += 256) {
        float c = -3e38f;
        if (j < N_) {
            const float* ej = emb + (size_t)j * D_;
            float dot = 0.f;
            #pragma unroll
            for (int d = 0; d < D_; ++d) dot += er[d] * ej[d];
            c = dot / (rni * nrm[j]);
        }
        cosL[j] = c;
    }
    __syncthreads();

    for (int k = 0; k < K_; ++k) {
        float bv = -3e38f; int bi = 0x7fffffff;
        for (int j = t; j < 2048; j += 256) {
            float v = cosL[j];
            if (v > bv || (v == bv && j < bi)) { bv = v; bi = j; }
        }
        // wave (64-lane) reduce, lower-index tie break (matches lax.top_k stability)
        for (int off = 32; off; off >>= 1) {
            float ov = __shfl_down(bv, off);
            int   oi = __shfl_down(bi, off);
            if (ov > bv || (ov == bv && oi < bi)) { bv = ov; bi = oi; }
        }
        if ((t & 63) == 0) { redV[t >> 6] = bv; redI[t >> 6] = bi; }
        __syncthreads();
        if (t == 0) {
            for (int w2 = 1; w2 < 4; ++w2)
                if (redV[w2] > bv || (redV[w2] == bv && redI[w2] < bi)) { bv = redV[w2]; bi = redI[w2]; }
            topk[i * K_ + k] = bi;
            cosL[bi] = -3e38f;
        }
        __syncthreads();
    }
}

// ---------------------------------------------------------------- xh = x@W_lin  + scores (16 nodes/block)
__global__ __launch_bounds__(256) void k_lin(const float* __restrict__ x,
                                             const float* __restrict__ Wlin,
                                             const float* __restrict__ emb,
                                             const float* __restrict__ atti,
                                             const float* __restrict__ attj,
                                             const float* __restrict__ attei,
                                             const float* __restrict__ attej,
                                             float* __restrict__ xh,
                                             float* __restrict__ si,
                                             float* __restrict__ sj) {
    const int t  = threadIdx.x;
    const int n0 = blockIdx.x * 16;      // 16 nodes, same batch (2000 % 16 == 0)
    const int i0 = n0 % N_;
    __shared__ float xL[16 * F_];
    __shared__ float eL[16 * D_];

    for (int idx = t; idx < 16 * F_; idx += 256) xL[idx] = x[(size_t)n0 * F_ + idx];
    for (int idx = t; idx < 16 * D_; idx += 256) eL[idx] = emb[(size_t)i0 * D_ + idx];
    __syncthreads();

    float acc[16];
    #pragma unroll
    for (int r = 0; r < 16; ++r) acc[r] = 0.f;
    const int c = t;                     // output column 0..255
    for (int k = 0; k < F_; ++k) {
        float w = Wlin[(size_t)k * HD_ + c];
        #pragma unroll
        for (int r = 0; r < 16; ++r) acc[r] += xL[r * F_ + k] * w;
    }
    #pragma unroll
    for (int r = 0; r < 16; ++r) xh[(size_t)(n0 + r) * HD_ + c] = acc[r];

    // fused attention scores: head h = wave id (threads 64h..64h+63)
    const int h = t >> 6, d = t & 63;
    const float ai = atti[c], aj = attj[c], aei = attei[c], aej = attej[c];
    for (int r = 0; r < 16; ++r) {
        float e  = eL[r * D_ + d];
        float vi = acc[r] * ai + e * aei;
        float vj = acc[r] * aj + e * aej;
        for (int off = 32; off; off >>= 1) {
            vi += __shfl_xor(vi, off);
            vj += __shfl_xor(vj, off);
        }
        if (d == 0) {
            si[(size_t)(n0 + r) * H_ + h] = vi;
            sj[(size_t)(n0 + r) * H_ + h] = vj;
        }
    }
}

// ---------------------------------------------------------------- attention softmax + aggregate + FF (4 nodes/block)
__global__ __launch_bounds__(256) void k_attn(const float* __restrict__ xh,
                                              const float* __restrict__ si,
                                              const float* __restrict__ sj,
                                              const int* __restrict__ topk,
                                              const float* __restrict__ biasg,
                                              const float* __restrict__ Wff,
                                              const float* __restrict__ bff,
                                              float* __restrict__ out2) {
    const int t  = threadIdx.x;
    const int n0 = blockIdx.x * 4;
    __shared__ int   srcL[4][21];
    __shared__ float wA[4][H_][21];
    __shared__ float aggL[4][HD_];
    __shared__ float pL[4][4][D_];

    if (t < 84) {                         // 4 nodes * 21 edges
        const int r = t / 21, e = t % 21;
        const int n = n0 + r;
        const int i = n % N_;
        const int b = n / N_;
        int s; bool dead = false;
        if (e < K_) { int kk = topk[i * K_ + e]; s = b * N_ + kk; dead = (kk == i); }
        else        { s = n; }
        srcL[r][e] = s;
        #pragma unroll
        for (int h = 0; h < H_; ++h) {
            float a = si[(size_t)n * H_ + h] + sj[(size_t)s * H_ + h];
            a = a > 0.f ? a : 0.2f * a;   // leaky_relu(0.2)
            if (dead) a = -1e30f;         // removed self-loop (after lrelu, as in ref)
            wA[r][h][e] = a;
        }
    }
    __syncthreads();

    if (t < 16) {                         // softmax over 21 edges, per (node, head)
        const int r = t >> 2, h = t & 3;
        float m = -3e38f;
        for (int e = 0; e < 21; ++e) m = fmaxf(m, wA[r][h][e]);
        float sum = 0.f;
        for (int e = 0; e < 21; ++e) { float ex = expf(wA[r][h][e] - m); wA[r][h][e] = ex; sum += ex; }
        float inv = 1.f / (sum + 1e-16f);
        for (int e = 0; e < 21; ++e) wA[r][h][e] *= inv;
    }
    __syncthreads();

    {                                     // aggregate: c = tid, head = c>>6
        const int c = t, h = t >> 6;
        #pragma unroll
        for (int r = 0; r < 4; ++r) {
            float acc = 0.f;
            for (int e = 0; e < 21; ++e)
                acc += wA[r][h][e] * xh[(size_t)srcL[r][e] * HD_ + c];
            aggL[r][c] = acc + biasg[c];
        }
    }
    __syncthreads();

    {                                     // FF: out2 = agg @ W_ff + b_ff (split-K over 4 groups)
        const int g = t >> 6, d = t & 63;
        float accf[4] = {0.f, 0.f, 0.f, 0.f};
        for (int cc = 0; cc < 64; ++cc) {
            const int c = g * 64 + cc;
            float w = Wff[(size_t)c * D_ + d];
            #pragma unroll
            for (int r = 0; r < 4; ++r) accf[r] += aggL[r][c] * w;
        }
        #pragma unroll
        for (int r = 0; r < 4; ++r) pL[g][r][d] = accf[r];
    }
    __syncthreads();

    {
        const int r = t >> 6, d = t & 63;
        float o = pL[0][r][d] + pL[1][r][d] + pL[2][r][d] + pL[3][r][d] + bff[d];
        out2[(size_t)(n0 + r) * D_ + d] = o;
    }
}

// ---------------------------------------------------------------- BN1 stats (f64 partials + atomics)
__global__ __launch_bounds__(256) void k_red1(const float* __restrict__ out2,
                                              double* __restrict__ S,
                                              double* __restrict__ SS) {
    const int t = threadIdx.x;
    double s = 0.0, ss = 0.0;
    const int total = BN_ * D_;
    for (int idx = blockIdx.x * 256 + t; idx < total; idx += gridDim.x * 256) {
        float v = out2[idx];
        s += v; ss += (double)v * v;
    }
    __shared__ double sb[256], ssb[256];
    sb[t] = s; ssb[t] = ss;
    __syncthreads();
    if (t < 64) {   // stride is a multiple of 64 -> channel == t
        double a = sb[t] + sb[t + 64] + sb[t + 128] + sb[t + 192];
        double b = ssb[t] + ssb[t + 64] + ssb[t + 128] + ssb[t + 192];
        atomicAdd(&S[t], a);
        atomicAdd(&SS[t], b);
    }
}

// ---------------------------------------------------------------- BN1 apply + *emb + BN2 stats
__global__ __launch_bounds__(256) void k_bn1(const float* __restrict__ out2,
                                             const float* __restrict__ emb,
                                             const double* __restrict__ S1,
                                             const double* __restrict__ SS1,
                                             const float* __restrict__ g1,
                                             const float* __restrict__ b1,
                                             float* __restrict__ hb,
                                             double* __restrict__ S2,
                                             double* __restrict__ SS2) {
    const int t = threadIdx.x;
    __shared__ float scale[64], shift[64];
    if (t < 64) {
        double mu  = S1[t] / (double)BN_;
        double var = SS1[t] / (double)BN_ - mu * mu;
        float rstd = rsqrtf((float)var + EPS_);
        float sc   = rstd * g1[t];
        scale[t] = sc;
        shift[t] = b1[t] - (float)mu * sc;
    }
    __syncthreads();
    const int d = t & 63;
    double s = 0.0, ss = 0.0;
    const int total = BN_ * D_;
    for (int idx = blockIdx.x * 256 + t; idx < total; idx += gridDim.x * 256) {
        float v = out2[idx];
        v = v * scale[d] + shift[d];
        v = fmaxf(v, 0.f);
        int n = idx >> 6;          // node index
        int i = n % N_;
        v *= emb[(size_t)i * D_ + d];
        hb[idx] = v;
        s += v; ss += (double)v * v;
    }
    __shared__ double sb[256], ssb[256];
    sb[t] = s; ssb[t] = ss;
    __syncthreads();
    if (t < 64) {
        double a = sb[t] + sb[t + 64] + sb[t + 128] + sb[t + 192];
        double b = ssb[t] + ssb[t + 64] + ssb[t + 128] + ssb[t + 192];
        atomicAdd(&S2[t], a);
        atomicAdd(&SS2[t], b);
    }
}

// ---------------------------------------------------------------- BN2 apply + out = h@W_out + b_out (16 nodes/block)
__global__ __launch_bounds__(256) void k_out(const float* __restrict__ hb,
                                             const double* __restrict__ S2,
                                             const double* __restrict__ SS2,
                                             const float* __restrict__ g2,
                                             const float* __restrict__ b2,
                                             const float* __restrict__ Wout,
                                             const float* __restrict__ bout,
                                             float* __restrict__ out) {
    const int t  = threadIdx.x;
    const int n0 = blockIdx.x * 16;
    __shared__ float scale[64], shift[64];
    __shared__ float hL[16 * D_];
    if (t < 64) {
        double mu  = S2[t] / (double)BN_;
        double var = SS2[t] / (double)BN_ - mu * mu;
        float rstd = rsqrtf((float)var + EPS_);
        float sc   = rstd * g2[t];
        scale[t] = sc;
        shift[t] = b2[t] - (float)mu * sc;
    }
    __syncthreads();
    for (int idx = t; idx < 16 * D_; idx += 256) {
        float v = hb[(size_t)n0 * D_ + idx];
        int d = idx & 63;
        v = fmaxf(v * scale[d] + shift[d], 0.f);
        hL[idx] = v;
    }
    __syncthreads();
    if (t < OW_) {
        float acc[16];
        #pragma unroll
        for (int r = 0; r < 16; ++r) acc[r] = 0.f;
        for (int d = 0; d < D_; ++d) {
            float w = Wout[(size_t)d * OW_ + t];
            #pragma unroll
            for (int r = 0; r < 16; ++r) acc[r] += hL[r * D_ + d] * w;
        }
        float bo = bout[t];
        #pragma unroll
        for (int r = 0; r < 16; ++r) out[(size_t)(n0 + r) * OW_ + t] = acc[r] + bo;
    }
}

// ---------------------------------------------------------------- launch
extern "C" void kernel_launch(void* const* d_in, const int* in_sizes, int n_in,
                              void* d_out, int out_size, void* d_ws, size_t ws_size,
                              hipStream_t stream) {
    const float* data  = (const float*)d_in[0];
    const float* emb   = (const float*)d_in[1];
    const float* Wlin  = (const float*)d_in[2];
    const float* atti  = (const float*)d_in[3];
    const float* attj  = (const float*)d_in[4];
    const float* attei = (const float*)d_in[5];
    const float* attej = (const float*)d_in[6];
    const float* biasg = (const float*)d_in[7];
    const float* Wff   = (const float*)d_in[8];
    const float* bff   = (const float*)d_in[9];
    const float* g1    = (const float*)d_in[10];
    const float* b1    = (const float*)d_in[11];
    const float* g2    = (const float*)d_in[12];
    const float* b2    = (const float*)d_in[13];
    const float* Wout  = (const float*)d_in[14];
    const float* bout  = (const float*)d_in[15];
    float* out = (float*)d_out;

    char* w = (char*)d_ws;
    size_t off = 0;
    auto alloc = [&](size_t bytes) -> void* {
        void* p = w + off;
        off += (bytes + 255) & ~(size_t)255;
        return p;
    };
    float*  nrm  = (float*) alloc((size_t)N_ * sizeof(float));
    int*    topk = (int*)   alloc((size_t)N_ * K_ * sizeof(int));
    float*  xh   = (float*) alloc((size_t)BN_ * HD_ * sizeof(float));   // 32.8 MB
    float*  si   = (float*) alloc((size_t)BN_ * H_ * sizeof(float));
    float*  sj   = (float*) alloc((size_t)BN_ * H_ * sizeof(float));
    float*  out2 = (float*) alloc((size_t)BN_ * D_ * sizeof(float));    // 8.2 MB
    float*  hb   = (float*) alloc((size_t)BN_ * D_ * sizeof(float));    // 8.2 MB
    double* S1   = (double*)alloc(64 * sizeof(double));
    double* SS1  = (double*)alloc(64 * sizeof(double));
    double* S2   = (double*)alloc(64 * sizeof(double));
    double* SS2  = (double*)alloc(64 * sizeof(double));

    // S1/SS1/S2/SS2 are contiguous (each 512 B, 256-aligned) — zero them every call
    hipMemsetAsync(S1, 0, 4 * 512, stream);

    hipLaunchKernelGGL(k_norms, dim3(8),        dim3(256), 0, stream, emb, nrm);
    hipLaunchKernelGGL(k_topk,  dim3(N_),       dim3(256), 0, stream, emb, nrm, topk);
    hipLaunchKernelGGL(k_lin,   dim3(BN_ / 16), dim3(256), 0, stream,
                       data, Wlin, emb, atti, attj, attei, attej, xh, si, sj);
    hipLaunchKernelGGL(k_attn,  dim3(BN_ / 4),  dim3(256), 0, stream,
                       xh, si, sj, topk, biasg, Wff, bff, out2);
    hipLaunchKernelGGL(k_red1,  dim3(128),      dim3(256), 0, stream, out2, S1, SS1);
    hipLaunchKernelGGL(k_bn1,   dim3(512),      dim3(256), 0, stream,
                       out2, emb, S1, SS1, g1, b1, hb, S2, SS2);
    hipLaunchKernelGGL(k_out,   dim3(BN_ / 16), dim3(256), 0, stream,
                       hb, S2, SS2, g2, b2, Wout, bout, out);
}

// Round 2
// 353.949 us; speedup vs baseline: 1.4604x; 1.4604x over previous
//
#include <hip/hip_runtime.h>
#include <math.h>

#define B_   16
#define N_   2000
#define F_   128
#define D_   64
#define H_   4
#define OW_  200
#define K_   20
#define BN_  (B_*N_)      // 32000
#define HD_  (H_*D_)      // 256
#define EPS_ 1e-5f
#define NP_  2048         // padded N for cos matrix

// ---------------------------------------------------------------- norms
__global__ __launch_bounds__(256) void k_norms(const float* __restrict__ emb,
                                               float* __restrict__ nrm) {
    int i = blockIdx.x * blockDim.x + threadIdx.x;
    if (i < N_) {
        const float* e = emb + (size_t)i * D_;
        float s = 0.f;
        #pragma unroll
        for (int d = 0; d < D_; ++d) s += e[d] * e[d];
        nrm[i] = sqrtf(s);
    }
}

// ---------------------------------------------------------------- emb transpose (zero-padded cols)
__global__ __launch_bounds__(256) void k_trans(const float* __restrict__ emb,
                                               float* __restrict__ embT) {
    int idx = blockIdx.x * 256 + threadIdx.x;   // 64 * 2048 = 131072
    int k = idx >> 11, j = idx & (NP_ - 1);
    float v = (j < N_) ? emb[(size_t)j * D_ + k] : 0.f;
    embT[idx] = v;
}

// ---------------------------------------------------------------- cos tile GEMM: 16 rows x 256 cols / block
__global__ __launch_bounds__(256) void k_cos(const float* __restrict__ emb,
                                             const float* __restrict__ embT,
                                             const float* __restrict__ nrm,
                                             float* __restrict__ cosm) {
    const int t  = threadIdx.x;
    const int i0 = blockIdx.y * 16;
    const int j  = blockIdx.x * 256 + t;

    float acc[16];
    #pragma unroll
    for (int r = 0; r < 16; ++r) acc[r] = 0.f;

    for (int k = 0; k < D_; ++k) {
        float b = embT[k * NP_ + j];            // coalesced; embT L2-resident
        #pragma unroll
        for (int r = 0; r < 16; ++r)            // A addr wave-uniform -> s_load
            acc[r] = fmaf(emb[(size_t)(i0 + r) * D_ + k], b, acc[r]);
    }

    float nj = (j < N_) ? nrm[j] : 1.f;
    #pragma unroll
    for (int r = 0; r < 16; ++r) {
        float c = acc[r] / (nrm[i0 + r] * nj);  // same formula/order as round-0
        cosm[(size_t)(i0 + r) * NP_ + j] = c;
    }
}

// ---------------------------------------------------------------- top-k select: one wave per row, no barriers
__global__ __launch_bounds__(256) void k_sel(const float* __restrict__ cosm,
                                             int* __restrict__ topk) {
    const int t    = threadIdx.x;
    const int lane = t & 63;
    const int i    = blockIdx.x * 4 + (t >> 6);
    const float* row = cosm + (size_t)i * NP_;

    // slot s -> j = (s>>2)*256 + lane*4 + (s&3)
    float v[32];
    #pragma unroll
    for (int m = 0; m < 8; ++m) {
        float4 b = *(const float4*)&row[m * 256 + lane * 4];
        v[m * 4 + 0] = b.x; v[m * 4 + 1] = b.y;
        v[m * 4 + 2] = b.z; v[m * 4 + 3] = b.w;
    }
    #pragma unroll
    for (int s = 0; s < 32; ++s) {
        int j = (s >> 2) * 256 + lane * 4 + (s & 3);
        if (j >= N_) v[s] = -3e38f;
    }

    float bv = -3e38f; int bj = 0x7fffffff;
    #pragma unroll
    for (int s = 0; s < 32; ++s) {
        int j = (s >> 2) * 256 + lane * 4 + (s & 3);
        if (v[s] > bv || (v[s] == bv && j < bj)) { bv = v[s]; bj = j; }
    }

    for (int k = 0; k < K_; ++k) {
        float wv = bv; int wj = bj;
        #pragma unroll
        for (int off = 1; off < 64; off <<= 1) {   // all lanes end with winner
            float ov = __shfl_xor(wv, off);
            int   oj = __shfl_xor(wj, off);
            if (ov > wv || (ov == wv && oj < wj)) { wv = ov; wj = oj; }
        }
        if (lane == 0) topk[i * K_ + k] = wj;
        // branchless kill + full rescan (winner lane's slot dies; others unchanged)
        bv = -3e38f; bj = 0x7fffffff;
        #pragma unroll
        for (int s = 0; s < 32; ++s) {
            int j = (s >> 2) * 256 + lane * 4 + (s & 3);
            if (j == wj) v[s] = -3e38f;
            if (v[s] > bv || (v[s] == bv && j < bj)) { bv = v[s]; bj = j; }
        }
    }
}

// ---------------------------------------------------------------- xh = x@W_lin  + scores (16 nodes/block)
__global__ __launch_bounds__(256) void k_lin(const float* __restrict__ x,
                                             const float* __restrict__ Wlin,
                                             const float* __restrict__ emb,
                                             const float* __restrict__ atti,
                                             const float* __restrict__ attj,
                                             const float* __restrict__ attei,
                                             const float* __restrict__ attej,
                                             float* __restrict__ xh,
                                             float* __restrict__ si,
                                             float* __restrict__ sj) {
    const int t  = threadIdx.x;
    const int n0 = blockIdx.x * 16;      // 16 nodes, same batch (2000 % 16 == 0)
    const int i0 = n0 % N_;
    __shared__ float xL[16 * F_];
    __shared__ float eL[16 * D_];

    for (int idx = t; idx < 16 * F_; idx += 256) xL[idx] = x[(size_t)n0 * F_ + idx];
    for (int idx = t; idx < 16 * D_; idx += 256) eL[idx] = emb[(size_t)i0 * D_ + idx];
    __syncthreads();

    float acc[16];
    #pragma unroll
    for (int r = 0; r < 16; ++r) acc[r] = 0.f;
    const int c = t;                     // output column 0..255
    for (int k = 0; k < F_; ++k) {
        float w = Wlin[(size_t)k * HD_ + c];
        #pragma unroll
        for (int r = 0; r < 16; ++r) acc[r] += xL[r * F_ + k] * w;
    }
    #pragma unroll
    for (int r = 0; r < 16; ++r) xh[(size_t)(n0 + r) * HD_ + c] = acc[r];

    // fused attention scores: head h = wave id (threads 64h..64h+63)
    const int h = t >> 6, d = t & 63;
    const float ai = atti[c], aj = attj[c], aei = attei[c], aej = attej[c];
    for (int r = 0; r < 16; ++r) {
        float e  = eL[r * D_ + d];
        float vi = acc[r] * ai + e * aei;
        float vj = acc[r] * aj + e * aej;
        for (int off = 32; off; off >>= 1) {
            vi += __shfl_xor(vi, off);
            vj += __shfl_xor(vj, off);
        }
        if (d == 0) {
            si[(size_t)(n0 + r) * H_ + h] = vi;
            sj[(size_t)(n0 + r) * H_ + h] = vj;
        }
    }
}

// ---------------------------------------------------------------- attention softmax + aggregate + FF (4 nodes/block)
__global__ __launch_bounds__(256) void k_attn(const float* __restrict__ xh,
                                              const float* __restrict__ si,
                                              const float* __restrict__ sj,
                                              const int* __restrict__ topk,
                                              const float* __restrict__ biasg,
                                              const float* __restrict__ Wff,
                                              const float* __restrict__ bff,
                                              float* __restrict__ out2) {
    const int t  = threadIdx.x;
    const int n0 = blockIdx.x * 4;
    __shared__ int   srcL[4][21];
    __shared__ float wA[4][H_][21];
    __shared__ float aggL[4][HD_];
    __shared__ float pL[4][4][D_];

    if (t < 84) {                         // 4 nodes * 21 edges
        const int r = t / 21, e = t % 21;
        const int n = n0 + r;
        const int i = n % N_;
        const int b = n / N_;
        int s; bool dead = false;
        if (e < K_) { int kk = topk[i * K_ + e]; s = b * N_ + kk; dead = (kk == i); }
        else        { s = n; }
        srcL[r][e] = s;
        #pragma unroll
        for (int h = 0; h < H_; ++h) {
            float a = si[(size_t)n * H_ + h] + sj[(size_t)s * H_ + h];
            a = a > 0.f ? a : 0.2f * a;   // leaky_relu(0.2)
            if (dead) a = -1e30f;         // removed self-loop (after lrelu, as in ref)
            wA[r][h][e] = a;
        }
    }
    __syncthreads();

    if (t < 16) {                         // softmax over 21 edges, per (node, head)
        const int r = t >> 2, h = t & 3;
        float m = -3e38f;
        for (int e = 0; e < 21; ++e) m = fmaxf(m, wA[r][h][e]);
        float sum = 0.f;
        for (int e = 0; e < 21; ++e) { float ex = expf(wA[r][h][e] - m); wA[r][h][e] = ex; sum += ex; }
        float inv = 1.f / (sum + 1e-16f);
        for (int e = 0; e < 21; ++e) wA[r][h][e] *= inv;
    }
    __syncthreads();

    {                                     // aggregate: c = tid, head = c>>6
        const int c = t, h = t >> 6;
        #pragma unroll
        for (int r = 0; r < 4; ++r) {
            float acc = 0.f;
            for (int e = 0; e < 21; ++e)
                acc += wA[r][h][e] * xh[(size_t)srcL[r][e] * HD_ + c];
            aggL[r][c] = acc + biasg[c];
        }
    }
    __syncthreads();

    {                                     // FF: out2 = agg @ W_ff + b_ff (split-K over 4 groups)
        const int g = t >> 6, d = t & 63;
        float accf[4] = {0.f, 0.f, 0.f, 0.f};
        for (int cc = 0; cc < 64; ++cc) {
            const int c = g * 64 + cc;
            float w = Wff[(size_t)c * D_ + d];
            #pragma unroll
            for (int r = 0; r < 4; ++r) accf[r] += aggL[r][c] * w;
        }
        #pragma unroll
        for (int r = 0; r < 4; ++r) pL[g][r][d] = accf[r];
    }
    __syncthreads();

    {
        const int r = t >> 6, d = t & 63;
        float o = pL[0][r][d] + pL[1][r][d] + pL[2][r][d] + pL[3][r][d] + bff[d];
        out2[(size_t)(n0 + r) * D_ + d] = o;
    }
}

// ---------------------------------------------------------------- BN1 stats (f64 partials + atomics)
__global__ __launch_bounds__(256) void k_red1(const float* __restrict__ out2,
                                              double* __restrict__ S,
                                              double* __restrict__ SS) {
    const int t = threadIdx.x;
    double s = 0.0, ss = 0.0;
    const int total = BN_ * D_;
    for (int idx = blockIdx.x * 256 + t; idx < total; idx += gridDim.x * 256) {
        float v = out2[idx];
        s += v; ss += (double)v * v;
    }
    __shared__ double sb[256], ssb[256];
    sb[t] = s; ssb[t] = ss;
    __syncthreads();
    if (t < 64) {   // stride is a multiple of 64 -> channel == t
        double a = sb[t] + sb[t + 64] + sb[t + 128] + sb[t + 192];
        double b = ssb[t] + ssb[t + 64] + ssb[t + 128] + ssb[t + 192];
        atomicAdd(&S[t], a);
        atomicAdd(&SS[t], b);
    }
}

// ---------------------------------------------------------------- BN1 apply + *emb + BN2 stats
__global__ __launch_bounds__(256) void k_bn1(const float* __restrict__ out2,
                                             const float* __restrict__ emb,
                                             const double* __restrict__ S1,
                                             const double* __restrict__ SS1,
                                             const float* __restrict__ g1,
                                             const float* __restrict__ b1,
                                             float* __restrict__ hb,
                                             double* __restrict__ S2,
                                             double* __restrict__ SS2) {
    const int t = threadIdx.x;
    __shared__ float scale[64], shift[64];
    if (t < 64) {
        double mu  = S1[t] / (double)BN_;
        double var = SS1[t] / (double)BN_ - mu * mu;
        float rstd = rsqrtf((float)var + EPS_);
        float sc   = rstd * g1[t];
        scale[t] = sc;
        shift[t] = b1[t] - (float)mu * sc;
    }
    __syncthreads();
    const int d = t & 63;
    double s = 0.0, ss = 0.0;
    const int total = BN_ * D_;
    for (int idx = blockIdx.x * 256 + t; idx < total; idx += gridDim.x * 256) {
        float v = out2[idx];
        v = v * scale[d] + shift[d];
        v = fmaxf(v, 0.f);
        int n = idx >> 6;          // node index
        int i = n % N_;
        v *= emb[(size_t)i * D_ + d];
        hb[idx] = v;
        s += v; ss += (double)v * v;
    }
    __shared__ double sb[256], ssb[256];
    sb[t] = s; ssb[t] = ss;
    __syncthreads();
    if (t < 64) {
        double a = sb[t] + sb[t + 64] + sb[t + 128] + sb[t + 192];
        double b = ssb[t] + ssb[t + 64] + ssb[t + 128] + ssb[t + 192];
        atomicAdd(&S2[t], a);
        atomicAdd(&SS2[t], b);
    }
}

// ---------------------------------------------------------------- BN2 apply + out = h@W_out + b_out (16 nodes/block)
__global__ __launch_bounds__(256) void k_out(const float* __restrict__ hb,
                                             const double* __restrict__ S2,
                                             const double* __restrict__ SS2,
                                             const float* __restrict__ g2,
                                             const float* __restrict__ b2,
                                             const float* __restrict__ Wout,
                                             const float* __restrict__ bout,
                                             float* __restrict__ out) {
    const int t  = threadIdx.x;
    const int n0 = blockIdx.x * 16;
    __shared__ float scale[64], shift[64];
    __shared__ float hL[16 * D_];
    if (t < 64) {
        double mu  = S2[t] / (double)BN_;
        double var = SS2[t] / (double)BN_ - mu * mu;
        float rstd = rsqrtf((float)var + EPS_);
        float sc   = rstd * g2[t];
        scale[t] = sc;
        shift[t] = b2[t] - (float)mu * sc;
    }
    __syncthreads();
    for (int idx = t; idx < 16 * D_; idx += 256) {
        float v = hb[(size_t)n0 * D_ + idx];
        int d = idx & 63;
        v = fmaxf(v * scale[d] + shift[d], 0.f);
        hL[idx] = v;
    }
    __syncthreads();
    if (t < OW_) {
        float acc[16];
        #pragma unroll
        for (int r = 0; r < 16; ++r) acc[r] = 0.f;
        for (int d = 0; d < D_; ++d) {
            float w = Wout[(size_t)d * OW_ + t];
            #pragma unroll
            for (int r = 0; r < 16; ++r) acc[r] += hL[r * D_ + d] * w;
        }
        float bo = bout[t];
        #pragma unroll
        for (int r = 0; r < 16; ++r) out[(size_t)(n0 + r) * OW_ + t] = acc[r] + bo;
    }
}

// ---------------------------------------------------------------- launch
extern "C" void kernel_launch(void* const* d_in, const int* in_sizes, int n_in,
                              void* d_out, int out_size, void* d_ws, size_t ws_size,
                              hipStream_t stream) {
    const float* data  = (const float*)d_in[0];
    const float* emb   = (const float*)d_in[1];
    const float* Wlin  = (const float*)d_in[2];
    const float* atti  = (const float*)d_in[3];
    const float* attj  = (const float*)d_in[4];
    const float* attei = (const float*)d_in[5];
    const float* attej = (const float*)d_in[6];
    const float* biasg = (const float*)d_in[7];
    const float* Wff   = (const float*)d_in[8];
    const float* bff   = (const float*)d_in[9];
    const float* g1    = (const float*)d_in[10];
    const float* b1    = (const float*)d_in[11];
    const float* g2    = (const float*)d_in[12];
    const float* b2    = (const float*)d_in[13];
    const float* Wout  = (const float*)d_in[14];
    const float* bout  = (const float*)d_in[15];
    float* out = (float*)d_out;

    char* w = (char*)d_ws;
    size_t off = 0;
    auto alloc = [&](size_t bytes) -> void* {
        void* p = w + off;
        off += (bytes + 255) & ~(size_t)255;
        return p;
    };
    float*  nrm  = (float*) alloc((size_t)N_ * sizeof(float));
    int*    topk = (int*)   alloc((size_t)N_ * K_ * sizeof(int));
    // union region: {embT, cosm} live only during topk phase; xh reuses it after
    float*  xh   = (float*) alloc((size_t)BN_ * HD_ * sizeof(float));   // 32.8 MB
    float*  embT = xh;                                                  // 0.5 MB
    float*  cosm = xh + (size_t)D_ * NP_;                               // 16.4 MB
    float*  si   = (float*) alloc((size_t)BN_ * H_ * sizeof(float));
    float*  sj   = (float*) alloc((size_t)BN_ * H_ * sizeof(float));
    float*  out2 = (float*) alloc((size_t)BN_ * D_ * sizeof(float));    // 8.2 MB
    float*  hb   = (float*) alloc((size_t)BN_ * D_ * sizeof(float));    // 8.2 MB
    double* S1   = (double*)alloc(64 * sizeof(double));
    double* SS1  = (double*)alloc(64 * sizeof(double));
    double* S2   = (double*)alloc(64 * sizeof(double));
    double* SS2  = (double*)alloc(64 * sizeof(double));

    // S1/SS1/S2/SS2 are contiguous (each 512 B, 256-aligned) — zero them every call
    hipMemsetAsync(S1, 0, 4 * 512, stream);

    hipLaunchKernelGGL(k_norms, dim3(8),            dim3(256), 0, stream, emb, nrm);
    hipLaunchKernelGGL(k_trans, dim3(D_*NP_/256),   dim3(256), 0, stream, emb, embT);
    hipLaunchKernelGGL(k_cos,   dim3(NP_/256, N_/16), dim3(256), 0, stream,
                       emb, embT, nrm, cosm);
    hipLaunchKernelGGL(k_sel,   dim3(N_/4),         dim3(256), 0, stream, cosm, topk);
    hipLaunchKernelGGL(k_lin,   dim3(BN_ / 16),     dim3(256), 0, stream,
                       data, Wlin, emb, atti, attj, attei, attej, xh, si, sj);
    hipLaunchKernelGGL(k_attn,  dim3(BN_ / 4),      dim3(256), 0, stream,
                       xh, si, sj, topk, biasg, Wff, bff, out2);
    hipLaunchKernelGGL(k_red1,  dim3(128),          dim3(256), 0, stream, out2, S1, SS1);
    hipLaunchKernelGGL(k_bn1,   dim3(512),          dim3(256), 0, stream,
                       out2, emb, S1, SS1, g1, b1, hb, S2, SS2);
    hipLaunchKernelGGL(k_out,   dim3(BN_ / 16),     dim3(256), 0, stream,
                       hb, S2, SS2, g2, b2, Wout, bout, out);
}

// Round 3
// 345.018 us; speedup vs baseline: 1.4982x; 1.0259x over previous
//
#include <hip/hip_runtime.h>
#include <math.h>

#define B_   16
#define N_   2000
#define F_   128
#define D_   64
#define H_   4
#define OW_  200
#define K_   20
#define BN_  (B_*N_)      // 32000
#define HD_  (H_*D_)      // 256
#define EPS_ 1e-5f
#define NP_  2048         // padded N for cos matrix

// ---------------------------------------------------------------- norms
__global__ __launch_bounds__(256) void k_norms(const float* __restrict__ emb,
                                               float* __restrict__ nrm) {
    int i = blockIdx.x * blockDim.x + threadIdx.x;
    if (i < N_) {
        const float* e = emb + (size_t)i * D_;
        float s = 0.f;
        #pragma unroll
        for (int d = 0; d < D_; ++d) s += e[d] * e[d];
        nrm[i] = sqrtf(s);
    }
}

// ---------------------------------------------------------------- emb transpose (zero-padded cols)
__global__ __launch_bounds__(256) void k_trans(const float* __restrict__ emb,
                                               float* __restrict__ embT) {
    int idx = blockIdx.x * 256 + threadIdx.x;   // 64 * 2048 = 131072
    int k = idx >> 11, j = idx & (NP_ - 1);
    float v = (j < N_) ? emb[(size_t)j * D_ + k] : 0.f;
    embT[idx] = v;
}

// ---------------------------------------------------------------- cos tile GEMM: 16 rows x 256 cols / block
__global__ __launch_bounds__(256) void k_cos(const float* __restrict__ emb,
                                             const float* __restrict__ embT,
                                             const float* __restrict__ nrm,
                                             float* __restrict__ cosm) {
    const int t  = threadIdx.x;
    const int i0 = blockIdx.y * 16;
    const int j  = blockIdx.x * 256 + t;

    float acc[16];
    #pragma unroll
    for (int r = 0; r < 16; ++r) acc[r] = 0.f;

    for (int k = 0; k < D_; ++k) {
        float b = embT[k * NP_ + j];            // coalesced; embT L2-resident
        #pragma unroll
        for (int r = 0; r < 16; ++r)            // A addr wave-uniform -> s_load
            acc[r] = fmaf(emb[(size_t)(i0 + r) * D_ + k], b, acc[r]);
    }

    float nj = (j < N_) ? nrm[j] : 1.f;
    #pragma unroll
    for (int r = 0; r < 16; ++r) {
        float c = acc[r] / (nrm[i0 + r] * nj);  // same formula/order as round-0
        cosm[(size_t)(i0 + r) * NP_ + j] = c;
    }
}

// ---------------------------------------------------------------- top-k select: one wave per row, no barriers
__global__ __launch_bounds__(256) void k_sel(const float* __restrict__ cosm,
                                             int* __restrict__ topk) {
    const int t    = threadIdx.x;
    const int lane = t & 63;
    const int i    = blockIdx.x * 4 + (t >> 6);
    const float* row = cosm + (size_t)i * NP_;

    // slot s -> j = (s>>2)*256 + lane*4 + (s&3)
    float v[32];
    #pragma unroll
    for (int m = 0; m < 8; ++m) {
        float4 b = *(const float4*)&row[m * 256 + lane * 4];
        v[m * 4 + 0] = b.x; v[m * 4 + 1] = b.y;
        v[m * 4 + 2] = b.z; v[m * 4 + 3] = b.w;
    }
    #pragma unroll
    for (int s = 0; s < 32; ++s) {
        int j = (s >> 2) * 256 + lane * 4 + (s & 3);
        if (j >= N_) v[s] = -3e38f;
    }

    float bv = -3e38f; int bj = 0x7fffffff;
    #pragma unroll
    for (int s = 0; s < 32; ++s) {
        int j = (s >> 2) * 256 + lane * 4 + (s & 3);
        if (v[s] > bv || (v[s] == bv && j < bj)) { bv = v[s]; bj = j; }
    }

    for (int k = 0; k < K_; ++k) {
        float wv = bv; int wj = bj;
        #pragma unroll
        for (int off = 1; off < 64; off <<= 1) {   // all lanes end with winner
            float ov = __shfl_xor(wv, off);
            int   oj = __shfl_xor(wj, off);
            if (ov > wv || (ov == wv && oj < wj)) { wv = ov; wj = oj; }
        }
        if (lane == 0) topk[i * K_ + k] = wj;
        // branchless kill + full rescan (winner lane's slot dies; others unchanged)
        bv = -3e38f; bj = 0x7fffffff;
        #pragma unroll
        for (int s = 0; s < 32; ++s) {
            int j = (s >> 2) * 256 + lane * 4 + (s & 3);
            if (j == wj) v[s] = -3e38f;
            if (v[s] > bv || (v[s] == bv && j < bj)) { bv = v[s]; bj = j; }
        }
    }
}

// ---------------------------------------------------------------- xh = x@W_lin + scores
// 16 nodes/block; wave w -> rows 4w..4w+3, 64 lanes x float4 cover all 256 cols.
// Per 4-k step: 4 wave-uniform ds_read_b128 (broadcast) + 4 coalesced float4 W loads
// + 64 FMA -> VALU-bound (was 1 ds_read_b32 per FMA).
__global__ __launch_bounds__(256) void k_lin(const float* __restrict__ x,
                                             const float* __restrict__ Wlin,
                                             const float* __restrict__ emb,
                                             const float* __restrict__ atti,
                                             const float* __restrict__ attj,
                                             const float* __restrict__ attei,
                                             const float* __restrict__ attej,
                                             float* __restrict__ xh,
                                             float* __restrict__ si,
                                             float* __restrict__ sj) {
    const int t  = threadIdx.x;
    const int n0 = blockIdx.x * 16;      // 16 nodes, same batch (2000 % 16 == 0)
    const int i0 = n0 % N_;
    const int r0 = (t >> 6) * 4;         // wave's 4 rows
    const int c4 = (t & 63) * 4;         // this thread's 4 output cols

    __shared__ float xL[16 * F_];        // 8 KB, linear row-major

    for (int idx = t; idx < 16 * F_; idx += 256)   // stride-1 b32: conflict-free
        xL[idx] = x[(size_t)n0 * F_ + idx];
    __syncthreads();

    float acc[4][4];
    #pragma unroll
    for (int r = 0; r < 4; ++r)
        #pragma unroll
        for (int cc = 0; cc < 4; ++cc) acc[r][cc] = 0.f;

    for (int k4 = 0; k4 < F_; k4 += 4) {
        float xs[4][4];
        #pragma unroll
        for (int r = 0; r < 4; ++r) {
            float4 xv = *(const float4*)&xL[(r0 + r) * F_ + k4];  // wave-uniform -> broadcast
            xs[r][0] = xv.x; xs[r][1] = xv.y; xs[r][2] = xv.z; xs[r][3] = xv.w;
        }
        #pragma unroll
        for (int kk = 0; kk < 4; ++kk) {
            float4 w = *(const float4*)&Wlin[(size_t)(k4 + kk) * HD_ + c4];
            #pragma unroll
            for (int r = 0; r < 4; ++r) {
                acc[r][0] = fmaf(xs[r][kk], w.x, acc[r][0]);
                acc[r][1] = fmaf(xs[r][kk], w.y, acc[r][1]);
                acc[r][2] = fmaf(xs[r][kk], w.z, acc[r][2]);
                acc[r][3] = fmaf(xs[r][kk], w.w, acc[r][3]);
            }
        }
    }

    #pragma unroll
    for (int r = 0; r < 4; ++r) {
        float4 o; o.x = acc[r][0]; o.y = acc[r][1]; o.z = acc[r][2]; o.w = acc[r][3];
        *(float4*)&xh[(size_t)(n0 + r0 + r) * HD_ + c4] = o;
    }

    // attention scores: head h = (t&63)>>4 (16 lanes per head); d-range = 4*(t&15)
    const int h  = (t & 63) >> 4;
    const int de = 4 * (t & 15);
    float4 ai4  = *(const float4*)&atti[c4];
    float4 aj4  = *(const float4*)&attj[c4];
    float4 aei4 = *(const float4*)&attei[c4];
    float4 aej4 = *(const float4*)&attej[c4];
    #pragma unroll
    for (int r = 0; r < 4; ++r) {
        float4 e4 = *(const float4*)&emb[(size_t)(i0 + r0 + r) * D_ + de];
        float vi = acc[r][0] * ai4.x + e4.x * aei4.x
                 + acc[r][1] * ai4.y + e4.y * aei4.y
                 + acc[r][2] * ai4.z + e4.z * aei4.z
                 + acc[r][3] * ai4.w + e4.w * aei4.w;
        float vj = acc[r][0] * aj4.x + e4.x * aej4.x
                 + acc[r][1] * aj4.y + e4.y * aej4.y
                 + acc[r][2] * aj4.z + e4.z * aej4.z
                 + acc[r][3] * aj4.w + e4.w * aej4.w;
        #pragma unroll
        for (int off = 1; off < 16; off <<= 1) {   // reduce the 16 lanes of this head
            vi += __shfl_xor(vi, off);
            vj += __shfl_xor(vj, off);
        }
        if ((t & 15) == 0) {
            si[(size_t)(n0 + r0 + r) * H_ + h] = vi;
            sj[(size_t)(n0 + r0 + r) * H_ + h] = vj;
        }
    }
}

// ---------------------------------------------------------------- attention softmax + aggregate + FF (8 nodes/block)
#define RA_ 8
__global__ __launch_bounds__(256) void k_attn(const float* __restrict__ xh,
                                              const float* __restrict__ si,
                                              const float* __restrict__ sj,
                                              const int* __restrict__ topk,
                                              const float* __restrict__ biasg,
                                              const float* __restrict__ Wff,
                                              const float* __restrict__ bff,
                                              float* __restrict__ out2) {
    const int t  = threadIdx.x;
    const int n0 = blockIdx.x * RA_;
    __shared__ int   srcL[RA_][21];
    __shared__ float wA[RA_][H_][21];
    __shared__ float aggL[RA_][HD_];
    __shared__ float pL[4][RA_][D_];

    if (t < RA_ * 21) {                   // 8 nodes * 21 edges
        const int r = t / 21, e = t % 21;
        const int n = n0 + r;
        const int i = n % N_;
        const int b = n / N_;
        int s; bool dead = false;
        if (e < K_) { int kk = topk[i * K_ + e]; s = b * N_ + kk; dead = (kk == i); }
        else        { s = n; }
        srcL[r][e] = s;
        #pragma unroll
        for (int h = 0; h < H_; ++h) {
            float a = si[(size_t)n * H_ + h] + sj[(size_t)s * H_ + h];
            a = a > 0.f ? a : 0.2f * a;   // leaky_relu(0.2)
            if (dead) a = -1e30f;         // removed self-loop (after lrelu, as in ref)
            wA[r][h][e] = a;
        }
    }
    __syncthreads();

    if (t < RA_ * H_) {                   // softmax over 21 edges, per (node, head)
        const int r = t >> 2, h = t & 3;
        float m = -3e38f;
        for (int e = 0; e < 21; ++e) m = fmaxf(m, wA[r][h][e]);
        float sum = 0.f;
        for (int e = 0; e < 21; ++e) { float ex = expf(wA[r][h][e] - m); wA[r][h][e] = ex; sum += ex; }
        float inv = 1.f / (sum + 1e-16f);
        for (int e = 0; e < 21; ++e) wA[r][h][e] *= inv;
    }
    __syncthreads();

    {                                     // aggregate: c = tid, head = c>>6
        const int c = t, h = t >> 6;
        #pragma unroll
        for (int r = 0; r < RA_; ++r) {
            float acc = 0.f;
            for (int e = 0; e < 21; ++e)
                acc += wA[r][h][e] * xh[(size_t)srcL[r][e] * HD_ + c];
            aggL[r][c] = acc + biasg[c];
        }
    }
    __syncthreads();

    {                                     // FF: out2 = agg @ W_ff + b_ff (split-K over 4 groups)
        const int g = t >> 6, d = t & 63;
        float accf[RA_];
        #pragma unroll
        for (int r = 0; r < RA_; ++r) accf[r] = 0.f;
        for (int cc = 0; cc < 64; ++cc) {
            const int c = g * 64 + cc;
            float w = Wff[(size_t)c * D_ + d];
            #pragma unroll
            for (int r = 0; r < RA_; ++r) accf[r] += aggL[r][c] * w;
        }
        #pragma unroll
        for (int r = 0; r < RA_; ++r) pL[g][r][d] = accf[r];
    }
    __syncthreads();

    {                                     // 512 outputs / 256 threads -> 2 rows each
        const int r0 = (t >> 6) * 2, d = t & 63;
        #pragma unroll
        for (int rr = 0; rr < 2; ++rr) {
            const int r = r0 + rr;
            float o = pL[0][r][d] + pL[1][r][d] + pL[2][r][d] + pL[3][r][d] + bff[d];
            out2[(size_t)(n0 + r) * D_ + d] = o;
        }
    }
}

// ---------------------------------------------------------------- BN1 stats (f64 partials + atomics)
__global__ __launch_bounds__(256) void k_red1(const float* __restrict__ out2,
                                              double* __restrict__ S,
                                              double* __restrict__ SS) {
    const int t = threadIdx.x;
    double s = 0.0, ss = 0.0;
    const int total = BN_ * D_;
    for (int idx = blockIdx.x * 256 + t; idx < total; idx += gridDim.x * 256) {
        float v = out2[idx];
        s += v; ss += (double)v * v;
    }
    __shared__ double sb[256], ssb[256];
    sb[t] = s; ssb[t] = ss;
    __syncthreads();
    if (t < 64) {   // stride is a multiple of 64 -> channel == t
        double a = sb[t] + sb[t + 64] + sb[t + 128] + sb[t + 192];
        double b = ssb[t] + ssb[t + 64] + ssb[t + 128] + ssb[t + 192];
        atomicAdd(&S[t], a);
        atomicAdd(&SS[t], b);
    }
}

// ---------------------------------------------------------------- BN1 apply + *emb + BN2 stats
__global__ __launch_bounds__(256) void k_bn1(const float* __restrict__ out2,
                                             const float* __restrict__ emb,
                                             const double* __restrict__ S1,
                                             const double* __restrict__ SS1,
                                             const float* __restrict__ g1,
                                             const float* __restrict__ b1,
                                             float* __restrict__ hb,
                                             double* __restrict__ S2,
                                             double* __restrict__ SS2) {
    const int t = threadIdx.x;
    __shared__ float scale[64], shift[64];
    if (t < 64) {
        double mu  = S1[t] / (double)BN_;
        double var = SS1[t] / (double)BN_ - mu * mu;
        float rstd = rsqrtf((float)var + EPS_);
        float sc   = rstd * g1[t];
        scale[t] = sc;
        shift[t] = b1[t] - (float)mu * sc;
    }
    __syncthreads();
    const int d = t & 63;
    double s = 0.0, ss = 0.0;
    const int total = BN_ * D_;
    for (int idx = blockIdx.x * 256 + t; idx < total; idx += gridDim.x * 256) {
        float v = out2[idx];
        v = v * scale[d] + shift[d];
        v = fmaxf(v, 0.f);
        int n = idx >> 6;          // node index
        int i = n % N_;
        v *= emb[(size_t)i * D_ + d];
        hb[idx] = v;
        s += v; ss += (double)v * v;
    }
    __shared__ double sb[256], ssb[256];
    sb[t] = s; ssb[t] = ss;
    __syncthreads();
    if (t < 64) {
        double a = sb[t] + sb[t + 64] + sb[t + 128] + sb[t + 192];
        double b = ssb[t] + ssb[t + 64] + ssb[t + 128] + ssb[t + 192];
        atomicAdd(&S2[t], a);
        atomicAdd(&SS2[t], b);
    }
}

// ---------------------------------------------------------------- BN2 apply + out = h@W_out + b_out (16 nodes/block)
__global__ __launch_bounds__(256) void k_out(const float* __restrict__ hb,
                                             const double* __restrict__ S2,
                                             const double* __restrict__ SS2,
                                             const float* __restrict__ g2,
                                             const float* __restrict__ b2,
                                             const float* __restrict__ Wout,
                                             const float* __restrict__ bout,
                                             float* __restrict__ out) {
    const int t  = threadIdx.x;
    const int n0 = blockIdx.x * 16;
    __shared__ float scale[64], shift[64];
    __shared__ float hL[16 * D_];
    if (t < 64) {
        double mu  = S2[t] / (double)BN_;
        double var = SS2[t] / (double)BN_ - mu * mu;
        float rstd = rsqrtf((float)var + EPS_);
        float sc   = rstd * g2[t];
        scale[t] = sc;
        shift[t] = b2[t] - (float)mu * sc;
    }
    __syncthreads();
    for (int idx = t; idx < 16 * D_; idx += 256) {
        float v = hb[(size_t)n0 * D_ + idx];
        int d = idx & 63;
        v = fmaxf(v * scale[d] + shift[d], 0.f);
        hL[idx] = v;
    }
    __syncthreads();
    if (t < OW_) {
        float acc[16];
        #pragma unroll
        for (int r = 0; r < 16; ++r) acc[r] = 0.f;
        for (int d = 0; d < D_; ++d) {
            float w = Wout[(size_t)d * OW_ + t];
            #pragma unroll
            for (int r = 0; r < 16; ++r) acc[r] += hL[r * D_ + d] * w;
        }
        float bo = bout[t];
        #pragma unroll
        for (int r = 0; r < 16; ++r) out[(size_t)(n0 + r) * OW_ + t] = acc[r] + bo;
    }
}

// ---------------------------------------------------------------- launch
extern "C" void kernel_launch(void* const* d_in, const int* in_sizes, int n_in,
                              void* d_out, int out_size, void* d_ws, size_t ws_size,
                              hipStream_t stream) {
    const float* data  = (const float*)d_in[0];
    const float* emb   = (const float*)d_in[1];
    const float* Wlin  = (const float*)d_in[2];
    const float* atti  = (const float*)d_in[3];
    const float* attj  = (const float*)d_in[4];
    const float* attei = (const float*)d_in[5];
    const float* attej = (const float*)d_in[6];
    const float* biasg = (const float*)d_in[7];
    const float* Wff   = (const float*)d_in[8];
    const float* bff   = (const float*)d_in[9];
    const float* g1    = (const float*)d_in[10];
    const float* b1    = (const float*)d_in[11];
    const float* g2    = (const float*)d_in[12];
    const float* b2    = (const float*)d_in[13];
    const float* Wout  = (const float*)d_in[14];
    const float* bout  = (const float*)d_in[15];
    float* out = (float*)d_out;

    char* w = (char*)d_ws;
    size_t off = 0;
    auto alloc = [&](size_t bytes) -> void* {
        void* p = w + off;
        off += (bytes + 255) & ~(size_t)255;
        return p;
    };
    float*  nrm  = (float*) alloc((size_t)N_ * sizeof(float));
    int*    topk = (int*)   alloc((size_t)N_ * K_ * sizeof(int));
    // union region: {embT, cosm} live only during topk phase; xh reuses it after
    float*  xh   = (float*) alloc((size_t)BN_ * HD_ * sizeof(float));   // 32.8 MB
    float*  embT = xh;                                                  // 0.5 MB
    float*  cosm = xh + (size_t)D_ * NP_;                               // 16.4 MB
    float*  si   = (float*) alloc((size_t)BN_ * H_ * sizeof(float));
    float*  sj   = (float*) alloc((size_t)BN_ * H_ * sizeof(float));
    float*  out2 = (float*) alloc((size_t)BN_ * D_ * sizeof(float));    // 8.2 MB
    float*  hb   = (float*) alloc((size_t)BN_ * D_ * sizeof(float));    // 8.2 MB
    double* S1   = (double*)alloc(64 * sizeof(double));
    double* SS1  = (double*)alloc(64 * sizeof(double));
    double* S2   = (double*)alloc(64 * sizeof(double));
    double* SS2  = (double*)alloc(64 * sizeof(double));

    // S1/SS1/S2/SS2 are contiguous (each 512 B, 256-aligned) — zero them every call
    hipMemsetAsync(S1, 0, 4 * 512, stream);

    hipLaunchKernelGGL(k_norms, dim3(8),            dim3(256), 0, stream, emb, nrm);
    hipLaunchKernelGGL(k_trans, dim3(D_*NP_/256),   dim3(256), 0, stream, emb, embT);
    hipLaunchKernelGGL(k_cos,   dim3(NP_/256, N_/16), dim3(256), 0, stream,
                       emb, embT, nrm, cosm);
    hipLaunchKernelGGL(k_sel,   dim3(N_/4),         dim3(256), 0, stream, cosm, topk);
    hipLaunchKernelGGL(k_lin,   dim3(BN_ / 16),     dim3(256), 0, stream,
                       data, Wlin, emb, atti, attj, attei, attej, xh, si, sj);
    hipLaunchKernelGGL(k_attn,  dim3(BN_ / RA_),    dim3(256), 0, stream,
                       xh, si, sj, topk, biasg, Wff, bff, out2);
    hipLaunchKernelGGL(k_red1,  dim3(128),          dim3(256), 0, stream, out2, S1, SS1);
    hipLaunchKernelGGL(k_bn1,   dim3(512),          dim3(256), 0, stream,
                       out2, emb, S1, SS1, g1, b1, hb, S2, SS2);
    hipLaunchKernelGGL(k_out,   dim3(BN_ / 16),     dim3(256), 0, stream,
                       hb, S2, SS2, g2, b2, Wout, bout, out);
}

// Round 4
// 319.405 us; speedup vs baseline: 1.6183x; 1.0802x over previous
//
#include <hip/hip_runtime.h>
#include <math.h>

#define B_   16
#define N_   2000
#define F_   128
#define D_   64
#define H_   4
#define OW_  200
#define K_   20
#define BN_  (B_*N_)      // 32000
#define HD_  (H_*D_)      // 256
#define EPS_ 1e-5f
#define NP_  2048         // padded N for cos matrix

// ---------------------------------------------------------------- norms (padded to NP_ with 1.0)
__global__ __launch_bounds__(256) void k_norms(const float* __restrict__ emb,
                                               float* __restrict__ nrm) {
    int i = blockIdx.x * blockDim.x + threadIdx.x;
    if (i < N_) {
        const float* e = emb + (size_t)i * D_;
        float s = 0.f;
        #pragma unroll
        for (int d = 0; d < D_; ++d) s += e[d] * e[d];
        nrm[i] = sqrtf(s);
    } else if (i < NP_) {
        nrm[i] = 1.f;
    }
}

// ---------------------------------------------------------------- emb transpose (zero-padded cols)
__global__ __launch_bounds__(256) void k_trans(const float* __restrict__ emb,
                                               float* __restrict__ embT) {
    int idx = blockIdx.x * 256 + threadIdx.x;   // 64 * 2048 = 131072
    int k = idx >> 11, j = idx & (NP_ - 1);
    float v = (j < N_) ? emb[(size_t)j * D_ + k] : 0.f;
    embT[idx] = v;
}

// ---------------------------------------------------------------- cos tile GEMM: 16 rows x 256 cols / block
// wave w -> rows 4w..4w+3; lanes x float4 cover 256 cols. LDS-staged A, b128 uniform reads.
__global__ __launch_bounds__(256) void k_cos(const float* __restrict__ emb,
                                             const float* __restrict__ embT,
                                             const float* __restrict__ nrm,
                                             float* __restrict__ cosm) {
    const int t    = threadIdx.x;
    const int i0   = blockIdx.y * 16;
    const int r0   = (t >> 6) * 4;
    const int lane = t & 63;
    const int j4   = blockIdx.x * 256 + lane * 4;

    __shared__ float eL[16 * D_];        // 4 KB
    for (int idx = t; idx < 16 * D_; idx += 256)
        eL[idx] = emb[(size_t)i0 * D_ + idx];
    __syncthreads();

    float acc[4][4];
    #pragma unroll
    for (int r = 0; r < 4; ++r)
        #pragma unroll
        for (int cc = 0; cc < 4; ++cc) acc[r][cc] = 0.f;

    for (int k4 = 0; k4 < D_; k4 += 4) {
        float es[4][4];
        #pragma unroll
        for (int r = 0; r < 4; ++r) {
            float4 ev = *(const float4*)&eL[(r0 + r) * D_ + k4];   // wave-uniform broadcast
            es[r][0] = ev.x; es[r][1] = ev.y; es[r][2] = ev.z; es[r][3] = ev.w;
        }
        #pragma unroll
        for (int kk = 0; kk < 4; ++kk) {
            float4 b = *(const float4*)&embT[(size_t)(k4 + kk) * NP_ + j4];  // coalesced
            #pragma unroll
            for (int r = 0; r < 4; ++r) {
                acc[r][0] = fmaf(es[r][kk], b.x, acc[r][0]);
                acc[r][1] = fmaf(es[r][kk], b.y, acc[r][1]);
                acc[r][2] = fmaf(es[r][kk], b.z, acc[r][2]);
                acc[r][3] = fmaf(es[r][kk], b.w, acc[r][3]);
            }
        }
    }

    float4 nj = *(const float4*)&nrm[j4];   // pad lanes read 1.0
    #pragma unroll
    for (int r = 0; r < 4; ++r) {
        float ni = nrm[i0 + r0 + r];
        float4 o;
        o.x = acc[r][0] / (ni * nj.x);      // same formula/order as before
        o.y = acc[r][1] / (ni * nj.y);
        o.z = acc[r][2] / (ni * nj.z);
        o.w = acc[r][3] / (ni * nj.w);
        *(float4*)&cosm[(size_t)(i0 + r0 + r) * NP_ + j4] = o;
    }
}

// ---------------------------------------------------------------- top-k select: one wave per row, no barriers
__global__ __launch_bounds__(256) void k_sel(const float* __restrict__ cosm,
                                             int* __restrict__ topk) {
    const int t    = threadIdx.x;
    const int lane = t & 63;
    const int i    = blockIdx.x * 4 + (t >> 6);
    const float* row = cosm + (size_t)i * NP_;

    // slot s -> j = (s>>2)*256 + lane*4 + (s&3)
    float v[32];
    #pragma unroll
    for (int m = 0; m < 8; ++m) {
        float4 b = *(const float4*)&row[m * 256 + lane * 4];
        v[m * 4 + 0] = b.x; v[m * 4 + 1] = b.y;
        v[m * 4 + 2] = b.z; v[m * 4 + 3] = b.w;
    }
    #pragma unroll
    for (int s = 0; s < 32; ++s) {
        int j = (s >> 2) * 256 + lane * 4 + (s & 3);
        if (j >= N_) v[s] = -3e38f;
    }

    float bv = -3e38f; int bj = 0x7fffffff;
    #pragma unroll
    for (int s = 0; s < 32; ++s) {
        int j = (s >> 2) * 256 + lane * 4 + (s & 3);
        if (v[s] > bv || (v[s] == bv && j < bj)) { bv = v[s]; bj = j; }
    }

    for (int k = 0; k < K_; ++k) {
        float wv = bv; int wj = bj;
        #pragma unroll
        for (int off = 1; off < 64; off <<= 1) {   // all lanes end with winner
            float ov = __shfl_xor(wv, off);
            int   oj = __shfl_xor(wj, off);
            if (ov > wv || (ov == wv && oj < wj)) { wv = ov; wj = oj; }
        }
        if (lane == 0) topk[i * K_ + k] = wj;
        // branchless kill + full rescan (winner lane's slot dies; others unchanged)
        bv = -3e38f; bj = 0x7fffffff;
        #pragma unroll
        for (int s = 0; s < 32; ++s) {
            int j = (s >> 2) * 256 + lane * 4 + (s & 3);
            if (j == wj) v[s] = -3e38f;
            if (v[s] > bv || (v[s] == bv && j < bj)) { bv = v[s]; bj = j; }
        }
    }
}

// ---------------------------------------------------------------- xh = x@W_lin + scores
__global__ __launch_bounds__(256) void k_lin(const float* __restrict__ x,
                                             const float* __restrict__ Wlin,
                                             const float* __restrict__ emb,
                                             const float* __restrict__ atti,
                                             const float* __restrict__ attj,
                                             const float* __restrict__ attei,
                                             const float* __restrict__ attej,
                                             float* __restrict__ xh,
                                             float* __restrict__ si,
                                             float* __restrict__ sj) {
    const int t  = threadIdx.x;
    const int n0 = blockIdx.x * 16;      // 16 nodes, same batch (2000 % 16 == 0)
    const int i0 = n0 % N_;
    const int r0 = (t >> 6) * 4;         // wave's 4 rows
    const int c4 = (t & 63) * 4;         // this thread's 4 output cols

    __shared__ float xL[16 * F_];        // 8 KB, linear row-major

    for (int idx = t; idx < 16 * F_; idx += 256)   // stride-1 b32: conflict-free
        xL[idx] = x[(size_t)n0 * F_ + idx];
    __syncthreads();

    float acc[4][4];
    #pragma unroll
    for (int r = 0; r < 4; ++r)
        #pragma unroll
        for (int cc = 0; cc < 4; ++cc) acc[r][cc] = 0.f;

    for (int k4 = 0; k4 < F_; k4 += 4) {
        float xs[4][4];
        #pragma unroll
        for (int r = 0; r < 4; ++r) {
            float4 xv = *(const float4*)&xL[(r0 + r) * F_ + k4];  // wave-uniform -> broadcast
            xs[r][0] = xv.x; xs[r][1] = xv.y; xs[r][2] = xv.z; xs[r][3] = xv.w;
        }
        #pragma unroll
        for (int kk = 0; kk < 4; ++kk) {
            float4 w = *(const float4*)&Wlin[(size_t)(k4 + kk) * HD_ + c4];
            #pragma unroll
            for (int r = 0; r < 4; ++r) {
                acc[r][0] = fmaf(xs[r][kk], w.x, acc[r][0]);
                acc[r][1] = fmaf(xs[r][kk], w.y, acc[r][1]);
                acc[r][2] = fmaf(xs[r][kk], w.z, acc[r][2]);
                acc[r][3] = fmaf(xs[r][kk], w.w, acc[r][3]);
            }
        }
    }

    #pragma unroll
    for (int r = 0; r < 4; ++r) {
        float4 o; o.x = acc[r][0]; o.y = acc[r][1]; o.z = acc[r][2]; o.w = acc[r][3];
        *(float4*)&xh[(size_t)(n0 + r0 + r) * HD_ + c4] = o;
    }

    // attention scores: head h = (t&63)>>4 (16 lanes per head); d-range = 4*(t&15)
    const int h  = (t & 63) >> 4;
    const int de = 4 * (t & 15);
    float4 ai4  = *(const float4*)&atti[c4];
    float4 aj4  = *(const float4*)&attj[c4];
    float4 aei4 = *(const float4*)&attei[c4];
    float4 aej4 = *(const float4*)&attej[c4];
    #pragma unroll
    for (int r = 0; r < 4; ++r) {
        float4 e4 = *(const float4*)&emb[(size_t)(i0 + r0 + r) * D_ + de];
        float vi = acc[r][0] * ai4.x + e4.x * aei4.x
                 + acc[r][1] * ai4.y + e4.y * aei4.y
                 + acc[r][2] * ai4.z + e4.z * aei4.z
                 + acc[r][3] * ai4.w + e4.w * aei4.w;
        float vj = acc[r][0] * aj4.x + e4.x * aej4.x
                 + acc[r][1] * aj4.y + e4.y * aej4.y
                 + acc[r][2] * aj4.z + e4.z * aej4.z
                 + acc[r][3] * aj4.w + e4.w * aej4.w;
        #pragma unroll
        for (int off = 1; off < 16; off <<= 1) {   // reduce the 16 lanes of this head
            vi += __shfl_xor(vi, off);
            vj += __shfl_xor(vj, off);
        }
        if ((t & 15) == 0) {
            si[(size_t)(n0 + r0 + r) * H_ + h] = vi;
            sj[(size_t)(n0 + r0 + r) * H_ + h] = vj;
        }
    }
}

// ---------------------------------------------------------------- attention softmax + aggregate + FF (8 nodes/block)
// XCD-swizzled so each XCD owns contiguous batches -> xh batch slice cached in ONE L2.
#define RA_ 8
__global__ __launch_bounds__(256) void k_attn(const float* __restrict__ xh,
                                              const float* __restrict__ si,
                                              const float* __restrict__ sj,
                                              const int* __restrict__ topk,
                                              const float* __restrict__ biasg,
                                              const float* __restrict__ Wff,
                                              const float* __restrict__ bff,
                                              float* __restrict__ out2) {
    const int t   = threadIdx.x;
    const int nwg = BN_ / RA_;                            // 4000, %8==0
    const int swz = (blockIdx.x & 7) * (nwg >> 3) + (blockIdx.x >> 3);  // bijective
    const int n0  = swz * RA_;
    __shared__ int   srcL[RA_][21];
    __shared__ float wA[RA_][H_][21];
    __shared__ float aggL[RA_][HD_];
    __shared__ float pL[4][RA_][D_];

    if (t < RA_ * 21) {                   // 8 nodes * 21 edges
        const int r = t / 21, e = t % 21;
        const int n = n0 + r;
        const int i = n % N_;
        const int b = n / N_;
        int s; bool dead = false;
        if (e < K_) { int kk = topk[i * K_ + e]; s = b * N_ + kk; dead = (kk == i); }
        else        { s = n; }
        srcL[r][e] = s;
        #pragma unroll
        for (int h = 0; h < H_; ++h) {
            float a = si[(size_t)n * H_ + h] + sj[(size_t)s * H_ + h];
            a = a > 0.f ? a : 0.2f * a;   // leaky_relu(0.2)
            if (dead) a = -1e30f;         // removed self-loop (after lrelu, as in ref)
            wA[r][h][e] = a;
        }
    }
    __syncthreads();

    if (t < RA_ * H_) {                   // softmax over 21 edges, per (node, head)
        const int r = t >> 2, h = t & 3;
        float m = -3e38f;
        for (int e = 0; e < 21; ++e) m = fmaxf(m, wA[r][h][e]);
        float sum = 0.f;
        for (int e = 0; e < 21; ++e) { float ex = expf(wA[r][h][e] - m); wA[r][h][e] = ex; sum += ex; }
        float inv = 1.f / (sum + 1e-16f);
        for (int e = 0; e < 21; ++e) wA[r][h][e] *= inv;
    }
    __syncthreads();

    {   // aggregate: wave g -> rows 2g,2g+1; lanes x float4 cover 256 cols (1 KB/row/instr)
        const int g = t >> 6, lane = t & 63, c4 = lane * 4, h = lane >> 4;
        #pragma unroll
        for (int rr = 0; rr < 2; ++rr) {
            const int r = g * 2 + rr;
            float a0 = 0.f, a1 = 0.f, a2 = 0.f, a3 = 0.f;
            for (int e = 0; e < 21; ++e) {
                float wv = wA[r][h][e];
                float4 xv = *(const float4*)&xh[(size_t)srcL[r][e] * HD_ + c4];
                a0 = fmaf(wv, xv.x, a0); a1 = fmaf(wv, xv.y, a1);
                a2 = fmaf(wv, xv.z, a2); a3 = fmaf(wv, xv.w, a3);
            }
            float4 bg = *(const float4*)&biasg[c4];
            float4 o; o.x = a0 + bg.x; o.y = a1 + bg.y; o.z = a2 + bg.z; o.w = a3 + bg.w;
            *(float4*)&aggL[r][c4] = o;
        }
    }
    __syncthreads();

    {   // FF split-K over 4 groups; aggL read as b128 uniform
        const int g = t >> 6, d = t & 63;
        float accf[RA_];
        #pragma unroll
        for (int r = 0; r < RA_; ++r) accf[r] = 0.f;
        for (int c4 = g * 64; c4 < g * 64 + 64; c4 += 4) {
            float as[RA_][4];
            #pragma unroll
            for (int r = 0; r < RA_; ++r) {
                float4 av = *(const float4*)&aggL[r][c4];
                as[r][0] = av.x; as[r][1] = av.y; as[r][2] = av.z; as[r][3] = av.w;
            }
            #pragma unroll
            for (int kk = 0; kk < 4; ++kk) {
                float w = Wff[(size_t)(c4 + kk) * D_ + d];
                #pragma unroll
                for (int r = 0; r < RA_; ++r) accf[r] = fmaf(as[r][kk], w, accf[r]);
            }
        }
        #pragma unroll
        for (int r = 0; r < RA_; ++r) pL[g][r][d] = accf[r];
    }
    __syncthreads();

    {   // 512 outputs / 256 threads -> 2 rows each
        const int r0 = (t >> 6) * 2, d = t & 63;
        #pragma unroll
        for (int rr = 0; rr < 2; ++rr) {
            const int r = r0 + rr;
            float o = pL[0][r][d] + pL[1][r][d] + pL[2][r][d] + pL[3][r][d] + bff[d];
            out2[(size_t)(n0 + r) * D_ + d] = o;
        }
    }
}

// ---------------------------------------------------------------- BN1 stats (f64 partials + atomics)
__global__ __launch_bounds__(256) void k_red1(const float* __restrict__ out2,
                                              double* __restrict__ S,
                                              double* __restrict__ SS) {
    const int t = threadIdx.x;
    double s = 0.0, ss = 0.0;
    const int total = BN_ * D_;
    for (int idx = blockIdx.x * 256 + t; idx < total; idx += gridDim.x * 256) {
        float v = out2[idx];
        s += v; ss += (double)v * v;
    }
    __shared__ double sb[256], ssb[256];
    sb[t] = s; ssb[t] = ss;
    __syncthreads();
    if (t < 64) {   // stride is a multiple of 64 -> channel == t
        double a = sb[t] + sb[t + 64] + sb[t + 128] + sb[t + 192];
        double b = ssb[t] + ssb[t + 64] + ssb[t + 128] + ssb[t + 192];
        atomicAdd(&S[t], a);
        atomicAdd(&SS[t], b);
    }
}

// ---------------------------------------------------------------- BN1 apply + *emb + BN2 stats
__global__ __launch_bounds__(256) void k_bn1(const float* __restrict__ out2,
                                             const float* __restrict__ emb,
                                             const double* __restrict__ S1,
                                             const double* __restrict__ SS1,
                                             const float* __restrict__ g1,
                                             const float* __restrict__ b1,
                                             float* __restrict__ hb,
                                             double* __restrict__ S2,
                                             double* __restrict__ SS2) {
    const int t = threadIdx.x;
    __shared__ float scale[64], shift[64];
    if (t < 64) {
        double mu  = S1[t] / (double)BN_;
        double var = SS1[t] / (double)BN_ - mu * mu;
        float rstd = rsqrtf((float)var + EPS_);
        float sc   = rstd * g1[t];
        scale[t] = sc;
        shift[t] = b1[t] - (float)mu * sc;
    }
    __syncthreads();
    const int d = t & 63;
    double s = 0.0, ss = 0.0;
    const int total = BN_ * D_;
    for (int idx = blockIdx.x * 256 + t; idx < total; idx += gridDim.x * 256) {
        float v = out2[idx];
        v = v * scale[d] + shift[d];
        v = fmaxf(v, 0.f);
        int n = idx >> 6;          // node index
        int i = n % N_;
        v *= emb[(size_t)i * D_ + d];
        hb[idx] = v;
        s += v; ss += (double)v * v;
    }
    __shared__ double sb[256], ssb[256];
    sb[t] = s; ssb[t] = ss;
    __syncthreads();
    if (t < 64) {
        double a = sb[t] + sb[t + 64] + sb[t + 128] + sb[t + 192];
        double b = ssb[t] + ssb[t + 64] + ssb[t + 128] + ssb[t + 192];
        atomicAdd(&S2[t], a);
        atomicAdd(&SS2[t], b);
    }
}

// ---------------------------------------------------------------- BN2 apply + out = h@W_out + b_out (16 nodes/block)
__global__ __launch_bounds__(256) void k_out(const float* __restrict__ hb,
                                             const double* __restrict__ S2,
                                             const double* __restrict__ SS2,
                                             const float* __restrict__ g2,
                                             const float* __restrict__ b2,
                                             const float* __restrict__ Wout,
                                             const float* __restrict__ bout,
                                             float* __restrict__ out) {
    const int t  = threadIdx.x;
    const int n0 = blockIdx.x * 16;
    __shared__ float scale[64], shift[64];
    __shared__ float hL[16 * D_];
    if (t < 64) {
        double mu  = S2[t] / (double)BN_;
        double var = SS2[t] / (double)BN_ - mu * mu;
        float rstd = rsqrtf((float)var + EPS_);
        float sc   = rstd * g2[t];
        scale[t] = sc;
        shift[t] = b2[t] - (float)mu * sc;
    }
    __syncthreads();
    for (int idx = t; idx < 16 * D_; idx += 256) {
        float v = hb[(size_t)n0 * D_ + idx];
        int d = idx & 63;
        v = fmaxf(v * scale[d] + shift[d], 0.f);
        hL[idx] = v;
    }
    __syncthreads();
    if (t < OW_) {
        float acc[16];
        #pragma unroll
        for (int r = 0; r < 16; ++r) acc[r] = 0.f;
        for (int d4 = 0; d4 < D_; d4 += 4) {
            float hs[16][4];
            #pragma unroll
            for (int r = 0; r < 16; ++r) {
                float4 hv = *(const float4*)&hL[r * D_ + d4];   // uniform b128 broadcast
                hs[r][0] = hv.x; hs[r][1] = hv.y; hs[r][2] = hv.z; hs[r][3] = hv.w;
            }
            #pragma unroll
            for (int kk = 0; kk < 4; ++kk) {
                float w = Wout[(size_t)(d4 + kk) * OW_ + t];
                #pragma unroll
                for (int r = 0; r < 16; ++r) acc[r] = fmaf(hs[r][kk], w, acc[r]);
            }
        }
        float bo = bout[t];
        #pragma unroll
        for (int r = 0; r < 16; ++r) out[(size_t)(n0 + r) * OW_ + t] = acc[r] + bo;
    }
}

// ---------------------------------------------------------------- launch
extern "C" void kernel_launch(void* const* d_in, const int* in_sizes, int n_in,
                              void* d_out, int out_size, void* d_ws, size_t ws_size,
                              hipStream_t stream) {
    const float* data  = (const float*)d_in[0];
    const float* emb   = (const float*)d_in[1];
    const float* Wlin  = (const float*)d_in[2];
    const float* atti  = (const float*)d_in[3];
    const float* attj  = (const float*)d_in[4];
    const float* attei = (const float*)d_in[5];
    const float* attej = (const float*)d_in[6];
    const float* biasg = (const float*)d_in[7];
    const float* Wff   = (const float*)d_in[8];
    const float* bff   = (const float*)d_in[9];
    const float* g1    = (const float*)d_in[10];
    const float* b1    = (const float*)d_in[11];
    const float* g2    = (const float*)d_in[12];
    const float* b2    = (const float*)d_in[13];
    const float* Wout  = (const float*)d_in[14];
    const float* bout  = (const float*)d_in[15];
    float* out = (float*)d_out;

    char* w = (char*)d_ws;
    size_t off = 0;
    auto alloc = [&](size_t bytes) -> void* {
        void* p = w + off;
        off += (bytes + 255) & ~(size_t)255;
        return p;
    };
    float*  nrm  = (float*) alloc((size_t)NP_ * sizeof(float));         // padded
    int*    topk = (int*)   alloc((size_t)N_ * K_ * sizeof(int));
    // union region: {embT, cosm} live only during topk phase; xh reuses it after
    float*  xh   = (float*) alloc((size_t)BN_ * HD_ * sizeof(float));   // 32.8 MB
    float*  embT = xh;                                                  // 0.5 MB
    float*  cosm = xh + (size_t)D_ * NP_;                               // 16.4 MB
    float*  si   = (float*) alloc((size_t)BN_ * H_ * sizeof(float));
    float*  sj   = (float*) alloc((size_t)BN_ * H_ * sizeof(float));
    float*  out2 = (float*) alloc((size_t)BN_ * D_ * sizeof(float));    // 8.2 MB
    float*  hb   = (float*) alloc((size_t)BN_ * D_ * sizeof(float));    // 8.2 MB
    double* S1   = (double*)alloc(64 * sizeof(double));
    double* SS1  = (double*)alloc(64 * sizeof(double));
    double* S2   = (double*)alloc(64 * sizeof(double));
    double* SS2  = (double*)alloc(64 * sizeof(double));

    // S1/SS1/S2/SS2 are contiguous (each 512 B, 256-aligned) — zero them every call
    hipMemsetAsync(S1, 0, 4 * 512, stream);

    hipLaunchKernelGGL(k_norms, dim3(8),            dim3(256), 0, stream, emb, nrm);
    hipLaunchKernelGGL(k_trans, dim3(D_*NP_/256),   dim3(256), 0, stream, emb, embT);
    hipLaunchKernelGGL(k_cos,   dim3(NP_/256, N_/16), dim3(256), 0, stream,
                       emb, embT, nrm, cosm);
    hipLaunchKernelGGL(k_sel,   dim3(N_/4),         dim3(256), 0, stream, cosm, topk);
    hipLaunchKernelGGL(k_lin,   dim3(BN_ / 16),     dim3(256), 0, stream,
                       data, Wlin, emb, atti, attj, attei, attej, xh, si, sj);
    hipLaunchKernelGGL(k_attn,  dim3(BN_ / RA_),    dim3(256), 0, stream,
                       xh, si, sj, topk, biasg, Wff, bff, out2);
    hipLaunchKernelGGL(k_red1,  dim3(128),          dim3(256), 0, stream, out2, S1, SS1);
    hipLaunchKernelGGL(k_bn1,   dim3(512),          dim3(256), 0, stream,
                       out2, emb, S1, SS1, g1, b1, hb, S2, SS2);
    hipLaunchKernelGGL(k_out,   dim3(BN_ / 16),     dim3(256), 0, stream,
                       hb, S2, SS2, g2, b2, Wout, bout, out);
}

// Round 6
// 283.046 us; speedup vs baseline: 1.8262x; 1.1285x over previous
//
#include <hip/hip_runtime.h>
#include <math.h>

#define B_   16
#define N_   2000
#define F_   128
#define D_   64
#define H_   4
#define OW_  200
#define K_   20
#define BN_  (B_*N_)      // 32000
#define HD_  (H_*D_)      // 256
#define EPS_ 1e-5f
#define NP_  2048         // padded N for cos matrix

// ---------------------------------------------------------------- norms (padded to NP_ with 1.0)
__global__ __launch_bounds__(256) void k_norms(const float* __restrict__ emb,
                                               float* __restrict__ nrm) {
    int i = blockIdx.x * blockDim.x + threadIdx.x;
    if (i < N_) {
        const float* e = emb + (size_t)i * D_;
        float s = 0.f;
        #pragma unroll
        for (int d = 0; d < D_; ++d) s += e[d] * e[d];
        nrm[i] = sqrtf(s);
    } else if (i < NP_) {
        nrm[i] = 1.f;
    }
}

// ---------------------------------------------------------------- emb transpose (zero-padded cols)
__global__ __launch_bounds__(256) void k_trans(const float* __restrict__ emb,
                                               float* __restrict__ embT) {
    int idx = blockIdx.x * 256 + threadIdx.x;   // 64 * 2048 = 131072
    int k = idx >> 11, j = idx & (NP_ - 1);
    float v = (j < N_) ? emb[(size_t)j * D_ + k] : 0.f;
    embT[idx] = v;
}

// ---------------------------------------------------------------- cos tile GEMM: 16 rows x 256 cols / block
// wave w -> rows 4w..4w+3; lanes x float4 cover 256 cols. LDS-staged A, b128 uniform reads.
__global__ __launch_bounds__(256) void k_cos(const float* __restrict__ emb,
                                             const float* __restrict__ embT,
                                             const float* __restrict__ nrm,
                                             float* __restrict__ cosm) {
    const int t    = threadIdx.x;
    const int i0   = blockIdx.y * 16;
    const int r0   = (t >> 6) * 4;
    const int lane = t & 63;
    const int j4   = blockIdx.x * 256 + lane * 4;

    __shared__ float eL[16 * D_];        // 4 KB
    for (int idx = t; idx < 16 * D_; idx += 256)
        eL[idx] = emb[(size_t)i0 * D_ + idx];
    __syncthreads();

    float acc[4][4];
    #pragma unroll
    for (int r = 0; r < 4; ++r)
        #pragma unroll
        for (int cc = 0; cc < 4; ++cc) acc[r][cc] = 0.f;

    for (int k4 = 0; k4 < D_; k4 += 4) {
        float es[4][4];
        #pragma unroll
        for (int r = 0; r < 4; ++r) {
            float4 ev = *(const float4*)&eL[(r0 + r) * D_ + k4];   // wave-uniform broadcast
            es[r][0] = ev.x; es[r][1] = ev.y; es[r][2] = ev.z; es[r][3] = ev.w;
        }
        #pragma unroll
        for (int kk = 0; kk < 4; ++kk) {
            float4 b = *(const float4*)&embT[(size_t)(k4 + kk) * NP_ + j4];  // coalesced
            #pragma unroll
            for (int r = 0; r < 4; ++r) {
                acc[r][0] = fmaf(es[r][kk], b.x, acc[r][0]);
                acc[r][1] = fmaf(es[r][kk], b.y, acc[r][1]);
                acc[r][2] = fmaf(es[r][kk], b.z, acc[r][2]);
                acc[r][3] = fmaf(es[r][kk], b.w, acc[r][3]);
            }
        }
    }

    float4 nj = *(const float4*)&nrm[j4];   // pad lanes read 1.0
    #pragma unroll
    for (int r = 0; r < 4; ++r) {
        float ni = nrm[i0 + r0 + r];
        float4 o;
        o.x = acc[r][0] / (ni * nj.x);      // same formula/order as before
        o.y = acc[r][1] / (ni * nj.y);
        o.z = acc[r][2] / (ni * nj.z);
        o.w = acc[r][3] / (ni * nj.w);
        *(float4*)&cosm[(size_t)(i0 + r0 + r) * NP_ + j4] = o;
    }
}

// ---------------------------------------------------------------- top-k select: one wave per row, packed u64 keys
// key = (monotonic_u32(value) << 32) | (NP_-1-j): u64 max == (value desc, index asc),
// exactly lax.top_k order. Tree-reduce (depth 5) replaces the serial 32-slot chain;
// butterfly step = 1 shfl + cmp_u64 + 2 cndmask.
__device__ __forceinline__ unsigned long long kmax64(unsigned long long a,
                                                     unsigned long long b) {
    return a > b ? a : b;
}

__global__ __launch_bounds__(256) void k_sel(const float* __restrict__ cosm,
                                             int* __restrict__ topk) {
    const int t    = threadIdx.x;
    const int lane = t & 63;
    const int i    = blockIdx.x * 4 + (t >> 6);
    const float* row = cosm + (size_t)i * NP_;

    // slot s -> j = (s>>2)*256 + lane*4 + (s&3)
    unsigned long long key[32];
    #pragma unroll
    for (int m = 0; m < 8; ++m) {
        float4 b = *(const float4*)&row[m * 256 + lane * 4];
        float vv[4] = {b.x, b.y, b.z, b.w};
        #pragma unroll
        for (int q = 0; q < 4; ++q) {
            const int s = m * 4 + q;
            const int j = m * 256 + lane * 4 + q;
            unsigned int x  = __float_as_uint(vv[q]);
            unsigned int mv = (x & 0x80000000u) ? ~x : (x | 0x80000000u);
            unsigned long long kk =
                ((unsigned long long)mv << 32) | (unsigned int)(NP_ - 1 - j);
            key[s] = (j < N_) ? kk : 0ull;   // pad/killed slots: smallest key
        }
    }

    // local max: balanced tree, depth 5
    unsigned long long loc;
    {
        unsigned long long l1[16];
        #pragma unroll
        for (int s = 0; s < 16; ++s) l1[s] = kmax64(key[s], key[s + 16]);
        unsigned long long l2[8];
        #pragma unroll
        for (int s = 0; s < 8; ++s) l2[s] = kmax64(l1[s], l1[s + 8]);
        unsigned long long l3[4];
        #pragma unroll
        for (int s = 0; s < 4; ++s) l3[s] = kmax64(l2[s], l2[s + 4]);
        loc = kmax64(kmax64(l3[0], l3[2]), kmax64(l3[1], l3[3]));
    }

    for (int k = 0; k < K_; ++k) {
        // wave butterfly max: all lanes end with the global winner key
        unsigned long long w = loc;
        #pragma unroll
        for (int off = 1; off < 64; off <<= 1)
            w = kmax64(w, __shfl_xor(w, off, 64));

        if (lane == 0)
            topk[i * K_ + k] = (NP_ - 1) - (int)(unsigned int)(w & 0xFFFFFFFFu);

        // kill winner slot (independent per-slot compares), recompute local tree max
        #pragma unroll
        for (int s = 0; s < 32; ++s)
            if (key[s] == w) key[s] = 0ull;
        {
            unsigned long long l1[16];
            #pragma unroll
            for (int s = 0; s < 16; ++s) l1[s] = kmax64(key[s], key[s + 16]);
            unsigned long long l2[8];
            #pragma unroll
            for (int s = 0; s < 8; ++s) l2[s] = kmax64(l1[s], l1[s + 8]);
            unsigned long long l3[4];
            #pragma unroll
            for (int s = 0; s < 4; ++s) l3[s] = kmax64(l2[s], l2[s + 4]);
            loc = kmax64(kmax64(l3[0], l3[2]), kmax64(l3[1], l3[3]));
        }
    }
}

// ---------------------------------------------------------------- xh = x@W_lin + scores
__global__ __launch_bounds__(256) void k_lin(const float* __restrict__ x,
                                             const float* __restrict__ Wlin,
                                             const float* __restrict__ emb,
                                             const float* __restrict__ atti,
                                             const float* __restrict__ attj,
                                             const float* __restrict__ attei,
                                             const float* __restrict__ attej,
                                             float* __restrict__ xh,
                                             float* __restrict__ si,
                                             float* __restrict__ sj) {
    const int t  = threadIdx.x;
    const int n0 = blockIdx.x * 16;      // 16 nodes, same batch (2000 % 16 == 0)
    const int i0 = n0 % N_;
    const int r0 = (t >> 6) * 4;         // wave's 4 rows
    const int c4 = (t & 63) * 4;         // this thread's 4 output cols

    __shared__ float xL[16 * F_];        // 8 KB, linear row-major

    for (int idx = t; idx < 16 * F_; idx += 256)   // stride-1 b32: conflict-free
        xL[idx] = x[(size_t)n0 * F_ + idx];
    __syncthreads();

    float acc[4][4];
    #pragma unroll
    for (int r = 0; r < 4; ++r)
        #pragma unroll
        for (int cc = 0; cc < 4; ++cc) acc[r][cc] = 0.f;

    for (int k4 = 0; k4 < F_; k4 += 4) {
        float xs[4][4];
        #pragma unroll
        for (int r = 0; r < 4; ++r) {
            float4 xv = *(const float4*)&xL[(r0 + r) * F_ + k4];  // wave-uniform -> broadcast
            xs[r][0] = xv.x; xs[r][1] = xv.y; xs[r][2] = xv.z; xs[r][3] = xv.w;
        }
        #pragma unroll
        for (int kk = 0; kk < 4; ++kk) {
            float4 w = *(const float4*)&Wlin[(size_t)(k4 + kk) * HD_ + c4];
            #pragma unroll
            for (int r = 0; r < 4; ++r) {
                acc[r][0] = fmaf(xs[r][kk], w.x, acc[r][0]);
                acc[r][1] = fmaf(xs[r][kk], w.y, acc[r][1]);
                acc[r][2] = fmaf(xs[r][kk], w.z, acc[r][2]);
                acc[r][3] = fmaf(xs[r][kk], w.w, acc[r][3]);
            }
        }
    }

    #pragma unroll
    for (int r = 0; r < 4; ++r) {
        float4 o; o.x = acc[r][0]; o.y = acc[r][1]; o.z = acc[r][2]; o.w = acc[r][3];
        *(float4*)&xh[(size_t)(n0 + r0 + r) * HD_ + c4] = o;
    }

    // attention scores: head h = (t&63)>>4 (16 lanes per head); d-range = 4*(t&15)
    const int h  = (t & 63) >> 4;
    const int de = 4 * (t & 15);
    float4 ai4  = *(const float4*)&atti[c4];
    float4 aj4  = *(const float4*)&attj[c4];
    float4 aei4 = *(const float4*)&attei[c4];
    float4 aej4 = *(const float4*)&attej[c4];
    #pragma unroll
    for (int r = 0; r < 4; ++r) {
        float4 e4 = *(const float4*)&emb[(size_t)(i0 + r0 + r) * D_ + de];
        float vi = acc[r][0] * ai4.x + e4.x * aei4.x
                 + acc[r][1] * ai4.y + e4.y * aei4.y
                 + acc[r][2] * ai4.z + e4.z * aei4.z
                 + acc[r][3] * ai4.w + e4.w * aei4.w;
        float vj = acc[r][0] * aj4.x + e4.x * aej4.x
                 + acc[r][1] * aj4.y + e4.y * aej4.y
                 + acc[r][2] * aj4.z + e4.z * aej4.z
                 + acc[r][3] * aj4.w + e4.w * aej4.w;
        #pragma unroll
        for (int off = 1; off < 16; off <<= 1) {   // reduce the 16 lanes of this head
            vi += __shfl_xor(vi, off);
            vj += __shfl_xor(vj, off);
        }
        if ((t & 15) == 0) {
            si[(size_t)(n0 + r0 + r) * H_ + h] = vi;
            sj[(size_t)(n0 + r0 + r) * H_ + h] = vj;
        }
    }
}

// ---------------------------------------------------------------- attention softmax + aggregate + FF (8 nodes/block)
// XCD-swizzled so each XCD owns contiguous batches -> xh batch slice cached in ONE L2.
#define RA_ 8
__global__ __launch_bounds__(256) void k_attn(const float* __restrict__ xh,
                                              const float* __restrict__ si,
                                              const float* __restrict__ sj,
                                              const int* __restrict__ topk,
                                              const float* __restrict__ biasg,
                                              const float* __restrict__ Wff,
                                              const float* __restrict__ bff,
                                              float* __restrict__ out2) {
    const int t   = threadIdx.x;
    const int nwg = BN_ / RA_;                            // 4000, %8==0
    const int swz = (blockIdx.x & 7) * (nwg >> 3) + (blockIdx.x >> 3);  // bijective
    const int n0  = swz * RA_;
    __shared__ int   srcL[RA_][21];
    __shared__ float wA[RA_][H_][21];
    __shared__ float aggL[RA_][HD_];
    __shared__ float pL[4][RA_][D_];

    if (t < RA_ * 21) {                   // 8 nodes * 21 edges
        const int r = t / 21, e = t % 21;
        const int n = n0 + r;
        const int i = n % N_;
        const int b = n / N_;
        int s; bool dead = false;
        if (e < K_) { int kk = topk[i * K_ + e]; s = b * N_ + kk; dead = (kk == i); }
        else        { s = n; }
        srcL[r][e] = s;
        #pragma unroll
        for (int h = 0; h < H_; ++h) {
            float a = si[(size_t)n * H_ + h] + sj[(size_t)s * H_ + h];
            a = a > 0.f ? a : 0.2f * a;   // leaky_relu(0.2)
            if (dead) a = -1e30f;         // removed self-loop (after lrelu, as in ref)
            wA[r][h][e] = a;
        }
    }
    __syncthreads();

    if (t < RA_ * H_) {                   // softmax over 21 edges, per (node, head)
        const int r = t >> 2, h = t & 3;
        float m = -3e38f;
        for (int e = 0; e < 21; ++e) m = fmaxf(m, wA[r][h][e]);
        float sum = 0.f;
        for (int e = 0; e < 21; ++e) { float ex = expf(wA[r][h][e] - m); wA[r][h][e] = ex; sum += ex; }
        float inv = 1.f / (sum + 1e-16f);
        for (int e = 0; e < 21; ++e) wA[r][h][e] *= inv;
    }
    __syncthreads();

    {   // aggregate: wave g -> rows 2g,2g+1; lanes x float4 cover 256 cols (1 KB/row/instr)
        const int g = t >> 6, lane = t & 63, c4 = lane * 4, h = lane >> 4;
        #pragma unroll
        for (int rr = 0; rr < 2; ++rr) {
            const int r = g * 2 + rr;
            float a0 = 0.f, a1 = 0.f, a2 = 0.f, a3 = 0.f;
            for (int e = 0; e < 21; ++e) {
                float wv = wA[r][h][e];
                float4 xv = *(const float4*)&xh[(size_t)srcL[r][e] * HD_ + c4];
                a0 = fmaf(wv, xv.x, a0); a1 = fmaf(wv, xv.y, a1);
                a2 = fmaf(wv, xv.z, a2); a3 = fmaf(wv, xv.w, a3);
            }
            float4 bg = *(const float4*)&biasg[c4];
            float4 o; o.x = a0 + bg.x; o.y = a1 + bg.y; o.z = a2 + bg.z; o.w = a3 + bg.w;
            *(float4*)&aggL[r][c4] = o;
        }
    }
    __syncthreads();

    {   // FF split-K over 4 groups; aggL read as b128 uniform
        const int g = t >> 6, d = t & 63;
        float accf[RA_];
        #pragma unroll
        for (int r = 0; r < RA_; ++r) accf[r] = 0.f;
        for (int c4 = g * 64; c4 < g * 64 + 64; c4 += 4) {
            float as[RA_][4];
            #pragma unroll
            for (int r = 0; r < RA_; ++r) {
                float4 av = *(const float4*)&aggL[r][c4];
                as[r][0] = av.x; as[r][1] = av.y; as[r][2] = av.z; as[r][3] = av.w;
            }
            #pragma unroll
            for (int kk = 0; kk < 4; ++kk) {
                float w = Wff[(size_t)(c4 + kk) * D_ + d];
                #pragma unroll
                for (int r = 0; r < RA_; ++r) accf[r] = fmaf(as[r][kk], w, accf[r]);
            }
        }
        #pragma unroll
        for (int r = 0; r < RA_; ++r) pL[g][r][d] = accf[r];
    }
    __syncthreads();

    {   // 512 outputs / 256 threads -> 2 rows each
        const int r0 = (t >> 6) * 2, d = t & 63;
        #pragma unroll
        for (int rr = 0; rr < 2; ++rr) {
            const int r = r0 + rr;
            float o = pL[0][r][d] + pL[1][r][d] + pL[2][r][d] + pL[3][r][d] + bff[d];
            out2[(size_t)(n0 + r) * D_ + d] = o;
        }
    }
}

// ---------------------------------------------------------------- BN1 stats (f64 partials + atomics)
__global__ __launch_bounds__(256) void k_red1(const float* __restrict__ out2,
                                              double* __restrict__ S,
                                              double* __restrict__ SS) {
    const int t = threadIdx.x;
    double s = 0.0, ss = 0.0;
    const int total = BN_ * D_;
    for (int idx = blockIdx.x * 256 + t; idx < total; idx += gridDim.x * 256) {
        float v = out2[idx];
        s += v; ss += (double)v * v;
    }
    __shared__ double sb[256], ssb[256];
    sb[t] = s; ssb[t] = ss;
    __syncthreads();
    if (t < 64) {   // stride is a multiple of 64 -> channel == t
        double a = sb[t] + sb[t + 64] + sb[t + 128] + sb[t + 192];
        double b = ssb[t] + ssb[t + 64] + ssb[t + 128] + ssb[t + 192];
        atomicAdd(&S[t], a);
        atomicAdd(&SS[t], b);
    }
}

// ---------------------------------------------------------------- BN1 apply + *emb + BN2 stats
__global__ __launch_bounds__(256) void k_bn1(const float* __restrict__ out2,
                                             const float* __restrict__ emb,
                                             const double* __restrict__ S1,
                                             const double* __restrict__ SS1,
                                             const float* __restrict__ g1,
                                             const float* __restrict__ b1,
                                             float* __restrict__ hb,
                                             double* __restrict__ S2,
                                             double* __restrict__ SS2) {
    const int t = threadIdx.x;
    __shared__ float scale[64], shift[64];
    if (t < 64) {
        double mu  = S1[t] / (double)BN_;
        double var = SS1[t] / (double)BN_ - mu * mu;
        float rstd = rsqrtf((float)var + EPS_);
        float sc   = rstd * g1[t];
        scale[t] = sc;
        shift[t] = b1[t] - (float)mu * sc;
    }
    __syncthreads();
    const int d = t & 63;
    double s = 0.0, ss = 0.0;
    const int total = BN_ * D_;
    for (int idx = blockIdx.x * 256 + t; idx < total; idx += gridDim.x * 256) {
        float v = out2[idx];
        v = v * scale[d] + shift[d];
        v = fmaxf(v, 0.f);
        int n = idx >> 6;          // node index
        int i = n % N_;
        v *= emb[(size_t)i * D_ + d];
        hb[idx] = v;
        s += v; ss += (double)v * v;
    }
    __shared__ double sb[256], ssb[256];
    sb[t] = s; ssb[t] = ss;
    __syncthreads();
    if (t < 64) {
        double a = sb[t] + sb[t + 64] + sb[t + 128] + sb[t + 192];
        double b = ssb[t] + ssb[t + 64] + ssb[t + 128] + ssb[t + 192];
        atomicAdd(&S2[t], a);
        atomicAdd(&SS2[t], b);
    }
}

// ---------------------------------------------------------------- BN2 apply + out = h@W_out + b_out (16 nodes/block)
__global__ __launch_bounds__(256) void k_out(const float* __restrict__ hb,
                                             const double* __restrict__ S2,
                                             const double* __restrict__ SS2,
                                             const float* __restrict__ g2,
                                             const float* __restrict__ b2,
                                             const float* __restrict__ Wout,
                                             const float* __restrict__ bout,
                                             float* __restrict__ out) {
    const int t  = threadIdx.x;
    const int n0 = blockIdx.x * 16;
    __shared__ float scale[64], shift[64];
    __shared__ float hL[16 * D_];
    if (t < 64) {
        double mu  = S2[t] / (double)BN_;
        double var = SS2[t] / (double)BN_ - mu * mu;
        float rstd = rsqrtf((float)var + EPS_);
        float sc   = rstd * g2[t];
        scale[t] = sc;
        shift[t] = b2[t] - (float)mu * sc;
    }
    __syncthreads();
    for (int idx = t; idx < 16 * D_; idx += 256) {
        float v = hb[(size_t)n0 * D_ + idx];
        int d = idx & 63;
        v = fmaxf(v * scale[d] + shift[d], 0.f);
        hL[idx] = v;
    }
    __syncthreads();
    if (t < OW_) {
        float acc[16];
        #pragma unroll
        for (int r = 0; r < 16; ++r) acc[r] = 0.f;
        for (int d4 = 0; d4 < D_; d4 += 4) {
            float hs[16][4];
            #pragma unroll
            for (int r = 0; r < 16; ++r) {
                float4 hv = *(const float4*)&hL[r * D_ + d4];   // uniform b128 broadcast
                hs[r][0] = hv.x; hs[r][1] = hv.y; hs[r][2] = hv.z; hs[r][3] = hv.w;
            }
            #pragma unroll
            for (int kk = 0; kk < 4; ++kk) {
                float w = Wout[(size_t)(d4 + kk) * OW_ + t];
                #pragma unroll
                for (int r = 0; r < 16; ++r) acc[r] = fmaf(hs[r][kk], w, acc[r]);
            }
        }
        float bo = bout[t];
        #pragma unroll
        for (int r = 0; r < 16; ++r) out[(size_t)(n0 + r) * OW_ + t] = acc[r] + bo;
    }
}

// ---------------------------------------------------------------- launch
extern "C" void kernel_launch(void* const* d_in, const int* in_sizes, int n_in,
                              void* d_out, int out_size, void* d_ws, size_t ws_size,
                              hipStream_t stream) {
    const float* data  = (const float*)d_in[0];
    const float* emb   = (const float*)d_in[1];
    const float* Wlin  = (const float*)d_in[2];
    const float* atti  = (const float*)d_in[3];
    const float* attj  = (const float*)d_in[4];
    const float* attei = (const float*)d_in[5];
    const float* attej = (const float*)d_in[6];
    const float* biasg = (const float*)d_in[7];
    const float* Wff   = (const float*)d_in[8];
    const float* bff   = (const float*)d_in[9];
    const float* g1    = (const float*)d_in[10];
    const float* b1    = (const float*)d_in[11];
    const float* g2    = (const float*)d_in[12];
    const float* b2    = (const float*)d_in[13];
    const float* Wout  = (const float*)d_in[14];
    const float* bout  = (const float*)d_in[15];
    float* out = (float*)d_out;

    char* w = (char*)d_ws;
    size_t off = 0;
    auto alloc = [&](size_t bytes) -> void* {
        void* p = w + off;
        off += (bytes + 255) & ~(size_t)255;
        return p;
    };
    float*  nrm  = (float*) alloc((size_t)NP_ * sizeof(float));         // padded
    int*    topk = (int*)   alloc((size_t)N_ * K_ * sizeof(int));
    // union region: {embT, cosm} live only during topk phase; xh reuses it after
    float*  xh   = (float*) alloc((size_t)BN_ * HD_ * sizeof(float));   // 32.8 MB
    float*  embT = xh;                                                  // 0.5 MB
    float*  cosm = xh + (size_t)D_ * NP_;                               // 16.4 MB
    float*  si   = (float*) alloc((size_t)BN_ * H_ * sizeof(float));
    float*  sj   = (float*) alloc((size_t)BN_ * H_ * sizeof(float));
    float*  out2 = (float*) alloc((size_t)BN_ * D_ * sizeof(float));    // 8.2 MB
    float*  hb   = (float*) alloc((size_t)BN_ * D_ * sizeof(float));    // 8.2 MB
    double* S1   = (double*)alloc(64 * sizeof(double));
    double* SS1  = (double*)alloc(64 * sizeof(double));
    double* S2   = (double*)alloc(64 * sizeof(double));
    double* SS2  = (double*)alloc(64 * sizeof(double));

    // S1/SS1/S2/SS2 are contiguous (each 512 B, 256-aligned) — zero them every call
    hipMemsetAsync(S1, 0, 4 * 512, stream);

    hipLaunchKernelGGL(k_norms, dim3(8),            dim3(256), 0, stream, emb, nrm);
    hipLaunchKernelGGL(k_trans, dim3(D_*NP_/256),   dim3(256), 0, stream, emb, embT);
    hipLaunchKernelGGL(k_cos,   dim3(NP_/256, N_/16), dim3(256), 0, stream,
                       emb, embT, nrm, cosm);
    hipLaunchKernelGGL(k_sel,   dim3(N_/4),         dim3(256), 0, stream, cosm, topk);
    hipLaunchKernelGGL(k_lin,   dim3(BN_ / 16),     dim3(256), 0, stream,
                       data, Wlin, emb, atti, attj, attei, attej, xh, si, sj);
    hipLaunchKernelGGL(k_attn,  dim3(BN_ / RA_),    dim3(256), 0, stream,
                       xh, si, sj, topk, biasg, Wff, bff, out2);
    hipLaunchKernelGGL(k_red1,  dim3(128),          dim3(256), 0, stream, out2, S1, SS1);
    hipLaunchKernelGGL(k_bn1,   dim3(512),          dim3(256), 0, stream,
                       out2, emb, S1, SS1, g1, b1, hb, S2, SS2);
    hipLaunchKernelGGL(k_out,   dim3(BN_ / 16),     dim3(256), 0, stream,
                       hb, S2, SS2, g2, b2, Wout, bout, out);
}